// Round 10
// baseline (231.819 us; speedup 1.0000x reference)
//
#include <hip/hip_runtime.h>
#include <hip/hip_bf16.h>

typedef short s16x8 __attribute__((ext_vector_type(8)));
typedef float f32x2 __attribute__((ext_vector_type(2)));
typedef float f32x4 __attribute__((ext_vector_type(4)));
typedef float f32x16 __attribute__((ext_vector_type(16)));
typedef unsigned int u32;
typedef unsigned short u16;
typedef u32 u32x2v __attribute__((ext_vector_type(2)));
typedef u32 u32x4v __attribute__((ext_vector_type(4)));

#define TOK 216
#define T1 448
#define SP 110592
// fallback LDS map
#define BUF0 0
#define VOFF 57344
#define WOFF 122880
#define GBOFF 155648
#define LDS_OLD 157696
// workspace
#define TENB 28311552ull          // qn/kn bytes (110592*128*2)
#define VTB  29360128ull          // vt bytes (128*512*224*2)
#define WSNEED (2ull*TENB + VTB + 32768ull)
#define QSCALE 0.360673760f       // 0.25 * log2(e) -> use exp2

__device__ __forceinline__ u32 pack2(float a, float b) {
  u16 lo = __builtin_bit_cast(u16, __float2bfloat16(a));
  u16 hi = __builtin_bit_cast(u16, __float2bfloat16(b));
  return (u32)lo | ((u32)hi << 16);
}
__device__ __forceinline__ int swz(int row, int inner) {
  return inner ^ ((row & 7) << 4);
}
__device__ __forceinline__ void gload16(const void* g, void* l) {
  __builtin_amdgcn_global_load_lds(
      (const __attribute__((address_space(1))) void*)g,
      (__attribute__((address_space(3))) void*)l, 16, 0, 0);
}

__device__ __forceinline__ void ln_stats(const f32x2* xv, float& mA, float& rA,
                                         float& mB, float& rB) {
  float sA = 0.f, s2A = 0.f, sB = 0.f, s2B = 0.f;
#pragma unroll
  for (int c = 0; c < 32; ++c) {
    sA += xv[c].x; s2A += xv[c].x * xv[c].x;
    sB += xv[c].y; s2B += xv[c].y * xv[c].y;
  }
  sA += __shfl_xor(sA, 1); s2A += __shfl_xor(s2A, 1);
  sB += __shfl_xor(sB, 1); s2B += __shfl_xor(s2B, 1);
  sA += __shfl_xor(sA, 2); s2A += __shfl_xor(s2A, 2);
  sB += __shfl_xor(sB, 2); s2B += __shfl_xor(s2B, 2);
  mA = sA * (1.0f / 128.0f);
  rA = rsqrtf(s2A * (1.0f / 128.0f) - mA * mA + 1e-5f);
  mB = sB * (1.0f / 128.0f);
  rB = rsqrtf(s2B * (1.0f / 128.0f) - mB * mB + 1e-5f);
}

// ---- new-path attention step: K from LDS, V direct from vt[ch][wid][224] ----
template<bool MASK>
__device__ __forceinline__ void attn_stepD(const char* smem, const u16* __restrict__ vt,
                                           int wid, int h, int kt, s16x8 qfh,
                                           int lane, f32x16& acc, float& lsum) {
  const int half = lane >> 5;
  const int krow = kt * 32 + (lane & 31);
  s16x8 kf = *(const s16x8*)(smem + krow * 256 + swz(krow, h * 32 + half * 16));
  __builtin_amdgcn_s_setprio(1);
  f32x16 st = __builtin_amdgcn_mfma_f32_32x32x16_bf16(kf, qfh, (f32x16){}, 0, 0, 0);
  __builtin_amdgcn_s_setprio(0);
  // A-operand slot k holds V[token kt*32 + sigma~(k)], sigma~ = bit2<->bit3:
  // tokens {e..e+3, e+8..e+11} (+16 for vf1), e = 4*half -> 4x b64 direct loads
  const u16* vb = vt + ((h * 16 + (lane & 15)) * 512 + wid) * 224 + kt * 32 + 4 * half;
  u32x2v va0 = *(const u32x2v*)(vb);
  u32x2v va1 = *(const u32x2v*)(vb + 8);
  u32x2v va2 = *(const u32x2v*)(vb + 16);
  u32x2v va3 = *(const u32x2v*)(vb + 24);
  const int NR = MASK ? 12 : 16;
  u32 A[8];
  float ts0 = 0.f, ts1 = 0.f;
#pragma unroll
  for (int i = 0; i < 8; ++i) {
    float p0 = (2 * i < NR) ? __builtin_amdgcn_exp2f(st[2 * i]) : 0.f;
    float p1 = (2 * i + 1 < NR) ? __builtin_amdgcn_exp2f(st[2 * i + 1]) : 0.f;
    if (i & 1) ts1 += p0 + p1; else ts0 += p0 + p1;
    A[i] = pack2(p0, p1);
  }
  lsum += ts0 + ts1;
  s16x8 pf0 = __builtin_bit_cast(s16x8, (u32x4v){A[0], A[1], A[2], A[3]});
  s16x8 pf1 = __builtin_bit_cast(s16x8, (u32x4v){A[4], A[5], A[6], A[7]});
  s16x8 vf0 = __builtin_bit_cast(s16x8, (u32x4v){va0[0], va0[1], va1[0], va1[1]});
  s16x8 vf1 = __builtin_bit_cast(s16x8, (u32x4v){va2[0], va2[1], va3[0], va3[1]});
  __builtin_amdgcn_s_setprio(1);
  acc = __builtin_amdgcn_mfma_f32_32x32x16_bf16(vf0, pf0, acc, 0, 0, 0);
  acc = __builtin_amdgcn_mfma_f32_32x32x16_bf16(vf1, pf1, acc, 0, 0, 0);
  __builtin_amdgcn_s_setprio(0);
}

// ---- fallback attention step (LDS V, verified rounds 6-9) ----
template<bool MASK>
__device__ __forceinline__ void attn_stepF(const char* smem, int h, int kt,
                                           s16x8 qfh, int lane,
                                           f32x16& acc, float& lsum) {
  const int half = lane >> 5;
  const int krow = kt * 32 + (lane & 31);
  s16x8 kf = *(const s16x8*)(smem + BUF0 + krow * 256 +
                             swz(krow, h * 32 + half * 16));
  __builtin_amdgcn_s_setprio(1);
  f32x16 st = __builtin_amdgcn_mfma_f32_32x32x16_bf16(kf, qfh, (f32x16){}, 0, 0, 0);
  __builtin_amdgcn_s_setprio(0);
  const int vrow = h * 16 + (lane & 15);
  s16x8 vf0 = *(const s16x8*)(smem + VOFF + vrow * 512 +
                              swz(vrow, kt * 64 + half * 16));
  s16x8 vf1 = *(const s16x8*)(smem + VOFF + vrow * 512 +
                              swz(vrow, kt * 64 + 32 + half * 16));
  const int NR = MASK ? 12 : 16;
  u32 A[8];
  float ts0 = 0.f, ts1 = 0.f;
#pragma unroll
  for (int i = 0; i < 8; ++i) {
    float p0 = (2 * i < NR) ? __builtin_amdgcn_exp2f(st[2 * i]) : 0.f;
    float p1 = (2 * i + 1 < NR) ? __builtin_amdgcn_exp2f(st[2 * i + 1]) : 0.f;
    if (i & 1) ts1 += p0 + p1; else ts0 += p0 + p1;
    A[i] = pack2(p0, p1);
  }
  lsum += ts0 + ts1;
  s16x8 pf0 = __builtin_bit_cast(s16x8, (u32x4v){A[0], A[1], A[2], A[3]});
  s16x8 pf1 = __builtin_bit_cast(s16x8, (u32x4v){A[4], A[5], A[6], A[7]});
  __builtin_amdgcn_s_setprio(1);
  acc = __builtin_amdgcn_mfma_f32_32x32x16_bf16(vf0, pf0, acc, 0, 0, 0);
  acc = __builtin_amdgcn_mfma_f32_32x32x16_bf16(vf1, pf1, acc, 0, 0, 0);
  __builtin_amdgcn_s_setprio(0);
}

// ================= Kernel 1: LN + layout transform ==========================
// block (d,h): coalesced LN; writes qn/kn [g][ch], vt [ch][wid][224tok],
// block 2304: W -> wsg with sigma~-permuted columns (bf16).
extern "C" __global__ __launch_bounds__(256)
void lnpre_kernel(const float* __restrict__ qm, const float* __restrict__ km,
                  const float* __restrict__ vm,
                  const float* __restrict__ gq, const float* __restrict__ bq,
                  const float* __restrict__ gkv, const float* __restrict__ bkv,
                  const float* __restrict__ pw,
                  u16* __restrict__ qn, u16* __restrict__ kn,
                  u16* __restrict__ vt, u16* __restrict__ wsg) {
  const int tid = threadIdx.x;
  const int bid = blockIdx.x;
  if (bid >= 2304) {            // W: wsg[j][s] = W[j][sigma~(s)] bf16
#pragma unroll
    for (int k = 0; k < 32; ++k) {
      int idx = tid + 256 * k;
      int j = idx >> 6, cu = idx & 63;
      int c = 2 * cu;
      int cs = (c & ~12) | ((c & 4) << 1) | ((c & 8) >> 1);   // sigma~(c)
      ((u32*)wsg)[idx] = pack2(pw[j * 128 + cs], pw[j * 128 + cs + 1]);
    }
    return;
  }
  __shared__ float lf[6144];    // [128 ch][48 w] fp32
  __shared__ float gb[512];
  __shared__ u32 vstage32[64 * 48];   // [chpair][w] bf16x2
  const int d = bid / 48, h = bid - d * 48;
  const int dh = d * 2304 + h * 48;
  const int widbase = (d / 6) * 64 + (h / 6) * 8;
  const int tokbase = (d % 6) * 36 + (h % 6) * 6;
  if (tid < 128) {
    gb[tid] = gq[tid]; gb[128 + tid] = bq[tid];
    gb[256 + tid] = gkv[tid]; gb[384 + tid] = bkv[tid];
  }
  const int w = tid >> 2, q = tid & 3;
#pragma unroll 1
  for (int t = 0; t < 3; ++t) {
    const float* src = t == 0 ? qm : (t == 1 ? km : vm);
    const float* g = (t == 0) ? gb : gb + 256;
    const float* b = (t == 0) ? gb + 128 : gb + 384;
    const float scale = (t == 0) ? QSCALE : 1.0f;
#pragma unroll
    for (int k = 0; k < 6; ++k) {
      int j = tid + 256 * k;
      int ch = j / 12, wq = j - ch * 12;
      *(f32x4*)(lf + ch * 48 + wq * 4) =
          *(const f32x4*)(src + (long)ch * SP + dh + wq * 4);
    }
    __syncthreads();
    if (tid < 192) {
      float s = 0.f, s2 = 0.f;
#pragma unroll
      for (int c = 0; c < 32; ++c) {
        float x = lf[(q + 4 * c) * 48 + w];
        s += x; s2 += x * x;
      }
      s += __shfl_xor(s, 1); s2 += __shfl_xor(s2, 1);
      s += __shfl_xor(s, 2); s2 += __shfl_xor(s2, 2);
      float m = s * (1.f / 128.f);
      float r = rsqrtf(s2 * (1.f / 128.f) - m * m + 1e-5f);
      if (t < 2) {
        u16* dst = (t == 0) ? qn : kn;
        u32x4v* op = (u32x4v*)(dst + (long)(dh + w) * 128 + 32 * q);
#pragma unroll
        for (int v4 = 0; v4 < 4; ++v4) {
          u32x4v pk;
#pragma unroll
          for (int e = 0; e < 4; ++e) {
            int ch = 32 * q + v4 * 8 + 2 * e;
            float y0 = ((lf[ch * 48 + w] - m) * r * g[ch] + b[ch]) * scale;
            float y1 = ((lf[(ch + 1) * 48 + w] - m) * r * g[ch + 1] + b[ch + 1]) * scale;
            pk[e] = pack2(y0, y1);
          }
          op[v4] = pk;
        }
      } else {
#pragma unroll
        for (int cc2 = 0; cc2 < 16; ++cc2) {
          int ch = 32 * q + 2 * cc2;
          float y0 = (lf[ch * 48 + w] - m) * r * g[ch] + b[ch];
          float y1 = (lf[(ch + 1) * 48 + w] - m) * r * g[ch + 1] + b[ch + 1];
          vstage32[(16 * q + cc2) * 48 + w] = pack2(y0, y1);
        }
      }
    }
    __syncthreads();
  }
  // write vt[ch][wid][tok]: per (ch, window) a 6-token run (3 u32)
  for (int i = tid; i < 3072; i += 256) {
    int ch = i / 24, rem = i - ch * 24;
    int w2 = rem / 3, t2 = rem - w2 * 3;
    int wloc = w2 * 6 + t2 * 2;
    u32 va = vstage32[(ch >> 1) * 48 + wloc];
    u32 vb = vstage32[(ch >> 1) * 48 + wloc + 1];
    u32 lo = (ch & 1) ? (va >> 16) : (va & 0xFFFFu);
    u32 hi = (ch & 1) ? (vb >> 16) : (vb & 0xFFFFu);
    *(u32*)(vt + (long)(ch * 512 + widbase + w2) * 224 + tokbase + 2 * t2) =
        lo | (hi << 16);
  }
}

// ================= Kernel 2: attention + projection, K-LDS only =============
// 448 threads, LDS 57.9KB -> 2 blocks/CU, 512 blocks co-resident (1 epoch).
// One barrier. V/Q/W direct from global (L2). Projection in registers via
// sigma~-permuted W (oPk fragments are valid B-operands directly).
extern "C" __global__ __launch_bounds__(T1, 4)
void attn3_kernel(const u16* __restrict__ qn, const u16* __restrict__ kn,
                  const u16* __restrict__ vt, const u16* __restrict__ wsg,
                  const float* __restrict__ pb, float* __restrict__ out) {
  __shared__ __align__(16) char smem[57344 + 512];
  float* pbl = (float*)(smem + 57344);
  const int tid = threadIdx.x, lane = tid & 63, wv = tid >> 6;
  const int half = lane >> 5;
  const int bid = blockIdx.x;
  const int wid = ((bid & 7) << 6) | (bid >> 3);   // XCD chunked swizzle
  const int wd6 = (wid >> 6) * 6, wh6 = ((wid >> 3) & 7) * 6, ww6 = (wid & 7) * 6;
  const int boff = wd6 * 2304 + wh6 * 48 + ww6;

  // stage K rows 0..215 -> LDS (pre-swizzled source; rows 216-223 unread-or-masked)
  for (int uu = wv; uu < 54; uu += 7) {
    int row = 4 * uu + (lane >> 4);
    int tq = row / 6;
    int g = (wd6 + tq / 6) * 2304 + (wh6 + tq % 6) * 48 + ww6 + row % 6;
    gload16(kn + g * 128 + (((lane & 15) ^ (row & 7)) << 3), smem + uu * 1024);
  }
  if (tid < 128) pbl[tid] = pb[tid];

  // Q fragments direct from global (row clamped; pad lanes discarded at store)
  int qrow = wv * 32 + (lane & 31);
  if (qrow > 215) qrow = 215;
  int qg;
  {
    int tq = qrow / 6;
    qg = (wd6 + tq / 6) * 2304 + (wh6 + tq % 6) * 48 + ww6 + qrow % 6;
  }
  s16x8 qf[8];
#pragma unroll
  for (int h = 0; h < 8; ++h)
    qf[h] = *(const s16x8*)(qn + qg * 128 + h * 16 + half * 8);
  __syncthreads();   // K + pbl ready

  // attention: one head chain at a time (TLP from 14 waves/CU hides latency)
  u32 oPk[8][4];
#pragma unroll 1
  for (int h = 0; h < 8; ++h) {
    f32x16 a = {};
    float l = 0.f;
#pragma unroll 1
    for (int kt = 0; kt < 6; ++kt)
      attn_stepD<false>(smem, vt, wid, h, kt, qf[h], lane, a, l);
    attn_stepD<true>(smem, vt, wid, h, 6, qf[h], lane, a, l);
    l += __shfl_xor(l, 32);
    float li = 1.0f / l;
#pragma unroll
    for (int r = 0; r < 4; ++r)
      oPk[h][r] = pack2(a[2 * r] * li, a[2 * r + 1] * li);
  }

  // projection in registers: D[j][tok] = Wsg x O^T  (no barrier needed)
  const int tok = wv * 32 + (lane & 31);
  const bool valid = tok < TOK;
  int pos = 0;
  if (valid) {
    int tdd = tok / 36, trr = tok - tdd * 36;
    int thh = trr / 6, tww = trr - thh * 6;
    pos = boff + tdd * 2304 + thh * 48 + tww;
  }
#pragma unroll 1
  for (int js = 0; js < 4; ++js) {
    f32x16 acc = {};
#pragma unroll
    for (int hs = 0; hs < 8; ++hs) {
      s16x8 af = *(const s16x8*)(wsg + (js * 32 + (lane & 31)) * 128 +
                                 hs * 16 + half * 8);
      s16x8 bo = __builtin_bit_cast(s16x8,
          (u32x4v){oPk[hs][0], oPk[hs][1], oPk[hs][2], oPk[hs][3]});
      __builtin_amdgcn_s_setprio(1);
      acc = __builtin_amdgcn_mfma_f32_32x32x16_bf16(af, bo, acc, 0, 0, 0);
      __builtin_amdgcn_s_setprio(0);
    }
    if (valid) {
#pragma unroll
      for (int r = 0; r < 16; ++r) {
        int j = js * 32 + (r & 3) + 8 * (r >> 2) + 4 * half;
        out[j * SP + pos] = acc[r] + pbl[j];
      }
    }
  }
}

// ================= Fallback: fused single kernel (verified r7/r9) ===========
extern "C" __global__ __launch_bounds__(T1, 2)
void ca3d_kernel(const float* __restrict__ qm, const float* __restrict__ km,
                 const float* __restrict__ vm,
                 const float* __restrict__ gq, const float* __restrict__ bq,
                 const float* __restrict__ gkv, const float* __restrict__ bkv,
                 const float* __restrict__ pw, const float* __restrict__ pb,
                 float* __restrict__ out) {
  extern __shared__ __align__(16) char smem[];
  const int tid = threadIdx.x;
  const int lane = tid & 63;
  const int wv = tid >> 6;
  const int bid = blockIdx.x;
  const int wid = ((bid & 7) << 6) | (bid >> 3);
  const int wd = wid >> 6, wh = (wid >> 3) & 7, ww = wid & 7;
  const int boff = wd * 6 * 2304 + wh * 6 * 48 + ww * 6;

  for (int i = tid * 16; i < VOFF + 65536; i += T1 * 16)
    *(f32x4*)(smem + i) = (f32x4){};
  if (tid < 128) {
    ((float*)(smem + GBOFF))[tid] = gq[tid];
    ((float*)(smem + GBOFF + 512))[tid] = bq[tid];
    ((float*)(smem + GBOFF + 1024))[tid] = gkv[tid];
    ((float*)(smem + GBOFF + 1536))[tid] = bkv[tid];
  }
  const bool lnAct = tid < 432;
  const int tp = tid >> 2;
  const int cbase = (tid & 3) * 32;
  const int tA = tp * 2, tB = tA + 1;
  int td = tA / 36, tr_ = tA - td * 36;
  int th_ = tr_ / 6, tw_ = tr_ - th_ * 6;
  const int gpos = boff + td * 2304 + th_ * 48 + tw_;
  const int vposA = (tA & ~0xC) | ((tA & 4) << 1) | ((tA & 8) >> 1);

  f32x2 qv[32], kv[32], vv[32];
  if (lnAct) {
#pragma unroll
    for (int c = 0; c < 32; ++c)
      qv[c] = *(const f32x2*)(qm + gpos + (cbase + c) * SP);
#pragma unroll
    for (int c = 0; c < 32; ++c)
      kv[c] = *(const f32x2*)(km + gpos + (cbase + c) * SP);
  }
  __syncthreads();
  const float* gql = (const float*)(smem + GBOFF);
  const float* bql = (const float*)(smem + GBOFF + 512);
  const float* gkl = (const float*)(smem + GBOFF + 1024);
  const float* bkl = (const float*)(smem + GBOFF + 1536);
  if (lnAct) {
    float mA, rA, mB, rB;
    ln_stats(qv, mA, rA, mB, rB);
#pragma unroll
    for (int c = 0; c < 32; c += 2) {
      int cc = cbase + c;
      float g0 = gql[cc], g1 = gql[cc + 1], b0 = bql[cc], b1 = bql[cc + 1];
      *(u32*)(smem + BUF0 + tA * 256 + swz(tA, cc * 2)) =
          pack2(((qv[c].x - mA) * rA * g0 + b0) * QSCALE,
                ((qv[c + 1].x - mA) * rA * g1 + b1) * QSCALE);
      *(u32*)(smem + BUF0 + tB * 256 + swz(tB, cc * 2)) =
          pack2(((qv[c].y - mB) * rB * g0 + b0) * QSCALE,
                ((qv[c + 1].y - mB) * rB * g1 + b1) * QSCALE);
    }
#pragma unroll
    for (int c = 0; c < 32; ++c)
      vv[c] = *(const f32x2*)(vm + gpos + (cbase + c) * SP);
  }
  __syncthreads();
  s16x8 qf[8];
  {
    int row = wv * 32 + (lane & 31);
    int ib = (lane >> 5) * 16;
#pragma unroll
    for (int h = 0; h < 8; ++h)
      qf[h] = *(const s16x8*)(smem + BUF0 + row * 256 + swz(row, h * 32 + ib));
  }
  __syncthreads();
  if (lnAct) {
    {
      float mA, rA, mB, rB;
      ln_stats(kv, mA, rA, mB, rB);
#pragma unroll
      for (int c = 0; c < 32; c += 2) {
        int cc = cbase + c;
        float g0 = gkl[cc], g1 = gkl[cc + 1], b0 = bkl[cc], b1 = bkl[cc + 1];
        *(u32*)(smem + BUF0 + tA * 256 + swz(tA, cc * 2)) =
            pack2((kv[c].x - mA) * rA * g0 + b0,
                  (kv[c + 1].x - mA) * rA * g1 + b1);
        *(u32*)(smem + BUF0 + tB * 256 + swz(tB, cc * 2)) =
            pack2((kv[c].y - mB) * rB * g0 + b0,
                  (kv[c + 1].y - mB) * rB * g1 + b1);
      }
    }
    {
      float mA, rA, mB, rB;
      ln_stats(vv, mA, rA, mB, rB);
#pragma unroll
      for (int c = 0; c < 32; ++c) {
        int cc = cbase + c;
        float g0 = gkl[cc], b0 = bkl[cc];
        *(u32*)(smem + VOFF + cc * 512 + swz(cc, vposA * 2)) =
            pack2((vv[c].x - mA) * rA * g0 + b0,
                  (vv[c].y - mB) * rB * g0 + b0);
      }
    }
  }
  for (int i = tid; i < 8192; i += T1) {
    int j = i >> 6, c2 = i & 63;
    f32x2 w2 = *(const f32x2*)(pw + j * 128 + c2 * 2);
    *(u32*)(smem + WOFF + j * 256 + swz(j, c2 * 4)) = pack2(w2.x, w2.y);
  }
  __syncthreads();
  u32 oPk[8][4];
#pragma unroll
  for (int hp = 0; hp < 4; ++hp) {
    const int h0 = hp * 2, h1 = h0 + 1;
    f32x16 a0 = {}, a1 = {};
    float l0 = 0.f, l1 = 0.f;
#pragma unroll 1
    for (int kt = 0; kt < 6; ++kt) {
      attn_stepF<false>(smem, h0, kt, qf[h0], lane, a0, l0);
      attn_stepF<false>(smem, h1, kt, qf[h1], lane, a1, l1);
    }
    attn_stepF<true>(smem, h0, 6, qf[h0], lane, a0, l0);
    attn_stepF<true>(smem, h1, 6, qf[h1], lane, a1, l1);
    l0 += __shfl_xor(l0, 32);
    l1 += __shfl_xor(l1, 32);
    float i0 = 1.0f / l0, i1 = 1.0f / l1;
#pragma unroll
    for (int r = 0; r < 4; ++r) {
      oPk[h0][r] = pack2(a0[2 * r] * i0, a0[2 * r + 1] * i0);
      oPk[h1][r] = pack2(a1[2 * r] * i1, a1[2 * r + 1] * i1);
    }
  }
  __syncthreads();
  {
    const int tok = wv * 32 + (lane & 31);
    const int half = lane >> 5;
#pragma unroll
    for (int h = 0; h < 8; ++h) {
      int chb = h * 32 + half * 8;
      *(u32*)(smem + BUF0 + tok * 256 + swz(tok, chb))      = oPk[h][0];
      *(u32*)(smem + BUF0 + tok * 256 + swz(tok, chb + 4))  = oPk[h][1];
      *(u32*)(smem + BUF0 + tok * 256 + swz(tok, chb + 16)) = oPk[h][2];
      *(u32*)(smem + BUF0 + tok * 256 + swz(tok, chb + 20)) = oPk[h][3];
    }
  }
  __syncthreads();
#pragma unroll 1
  for (int ti = 0; ti < 2; ++ti) {
    int tt = wv * 2 + ti;
    int tok = tt * 16 + (lane & 15);
    s16x8 bfr[4];
#pragma unroll
    for (int kk = 0; kk < 4; ++kk)
      bfr[kk] = *(const s16x8*)(smem + BUF0 + tok * 256 +
                                swz(tok, kk * 64 + (lane >> 4) * 16));
    bool tokValid = tok < TOK;
    int tdd = tok / 36, trr = tok - tdd * 36;
    int thh = trr / 6, tww = trr - thh * 6;
    int pos = boff + tdd * 2304 + thh * 48 + tww;
#pragma unroll 1
    for (int jt = 0; jt < 8; ++jt) {
      f32x4 acc = {};
#pragma unroll
      for (int kk = 0; kk < 4; ++kk) {
        int rw = jt * 16 + (lane & 15);
        s16x8 af = *(const s16x8*)(smem + WOFF + rw * 256 +
                                   swz(rw, kk * 64 + (lane >> 4) * 16));
        acc = __builtin_amdgcn_mfma_f32_16x16x32_bf16(af, bfr[kk], acc, 0, 0, 0);
      }
      f32x4 pbv = *(const f32x4*)(pb + jt * 16 + (lane >> 4) * 4);
      if (tokValid) {
#pragma unroll
        for (int r = 0; r < 4; ++r) {
          int j = jt * 16 + (lane >> 4) * 4 + r;
          out[j * SP + pos] = acc[r] + pbv[r];
        }
      }
    }
  }
}

extern "C" void kernel_launch(void* const* d_in, const int* in_sizes, int n_in,
                              void* d_out, int out_size, void* d_ws, size_t ws_size,
                              hipStream_t stream) {
  const float* qm  = (const float*)d_in[0];
  const float* km  = (const float*)d_in[1];
  const float* vm  = (const float*)d_in[2];
  const float* gq  = (const float*)d_in[3];
  const float* bq  = (const float*)d_in[4];
  const float* gkv = (const float*)d_in[5];
  const float* bkv = (const float*)d_in[6];
  const float* pw  = (const float*)d_in[7];
  const float* pb  = (const float*)d_in[8];
  if (ws_size >= WSNEED) {
    u16* qn  = (u16*)d_ws;
    u16* kn  = (u16*)((char*)d_ws + TENB);
    u16* vt  = (u16*)((char*)d_ws + 2 * TENB);
    u16* wsg = (u16*)((char*)d_ws + 2 * TENB + VTB);
    hipLaunchKernelGGL(lnpre_kernel, dim3(2305), dim3(256), 0, stream,
                       qm, km, vm, gq, bq, gkv, bkv, pw, qn, kn, vt, wsg);
    hipLaunchKernelGGL(attn3_kernel, dim3(512), dim3(T1), 0, stream,
                       qn, kn, vt, wsg, pb, (float*)d_out);
  } else {
    hipLaunchKernelGGL(ca3d_kernel, dim3(512), dim3(T1), LDS_OLD, stream,
                       qm, km, vm, gq, bq, gkv, bkv, pw, pb, (float*)d_out);
  }
}

// Round 11
// 149.927 us; speedup vs baseline: 1.5462x; 1.5462x over previous
//
#include <hip/hip_runtime.h>
#include <hip/hip_bf16.h>

typedef short s16x8 __attribute__((ext_vector_type(8)));
typedef float f32x2 __attribute__((ext_vector_type(2)));
typedef float f32x4 __attribute__((ext_vector_type(4)));
typedef float f32x16 __attribute__((ext_vector_type(16)));
typedef unsigned int u32;
typedef unsigned short u16;
typedef u32 u32x4v __attribute__((ext_vector_type(4)));

#define TOK 216
#define T1 448              // fallback kernel block
#define T2 896              // attn2 block: 14 waves, 2 head-wavegroups
#define SP 110592           // 48*48*48
#define BUF0 0              // Q stage -> K -> obuf : 224 rows x 256B = 57344
#define VOFF 57344          // Vraw then Vt: 128 ch-rows x 512B = 65536
#define WOFF 122880         // proj_w bf16: 128 rows x 256B = 32768
#define GBOFF 155648        // (old path only) gamma/beta staging
#define LDS_OLD 157696
#define LDS_NEW 155648
#define TENB 28311552ull    // bytes per bf16 tensor copy (110592*128*2)
#define WSNEED (3ull*TENB + 32768ull)
#define QSCALE 0.360673760f // 0.25 * log2(e): QK^T yields scores*log2e -> exp2

// bf16 pack via builtin casts (RNE); compiler fuses to v_cvt_pk_bf16_f32.
__device__ __forceinline__ u32 pack2(float a, float b) {
  u16 lo = __builtin_bit_cast(u16, __float2bfloat16(a));
  u16 hi = __builtin_bit_cast(u16, __float2bfloat16(b));
  return (u32)lo | ((u32)hi << 16);
}
// &7 swizzle (V region + fallback kernel -- verified r6-r9 layout)
__device__ __forceinline__ int swz(int row, int inner) {
  return inner ^ ((row & 7) << 4);
}
// &15 swizzle (attn2 K/W/obuf tiles): spreads 32-row b128 reads over all 16
// 16B slots -> 4-way instead of 8-way bank conflict.
__device__ __forceinline__ int swzk(int row, int inner) {
  return inner ^ ((row & 15) << 4);
}
// async global->LDS, 16B/lane, dest = uniform base + lane*16
__device__ __forceinline__ void gload16(const void* g, void* l) {
  __builtin_amdgcn_global_load_lds(
      (const __attribute__((address_space(1))) void*)g,
      (__attribute__((address_space(3))) void*)l, 16, 0, 0);
}

// per token-pair LN stats over 128 ch held as 32 f32x2 across 4 lanes (old path)
__device__ __forceinline__ void ln_stats(const f32x2* xv, float& mA, float& rA,
                                         float& mB, float& rB) {
  float sA = 0.f, s2A = 0.f, sB = 0.f, s2B = 0.f;
#pragma unroll
  for (int c = 0; c < 32; ++c) {
    sA += xv[c].x; s2A += xv[c].x * xv[c].x;
    sB += xv[c].y; s2B += xv[c].y * xv[c].y;
  }
  sA += __shfl_xor(sA, 1); s2A += __shfl_xor(s2A, 1);
  sB += __shfl_xor(sB, 1); s2B += __shfl_xor(s2B, 1);
  sA += __shfl_xor(sA, 2); s2A += __shfl_xor(s2A, 2);
  sB += __shfl_xor(sB, 2); s2B += __shfl_xor(s2B, 2);
  mA = sA * (1.0f / 128.0f);
  rA = rsqrtf(s2A * (1.0f / 128.0f) - mA * mA + 1e-5f);
  mB = sB * (1.0f / 128.0f);
  rB = rsqrtf(s2B * (1.0f / 128.0f) - mB * mB + 1e-5f);
}

// attn2 step: NO setprio (scheduling fences removed so the compiler can
// pipeline across steps); K via swzk, V via swz. No-max softmax (exp2,
// log2e folded into Q). sigma-permuted V -> packed P regs ARE the PV B-frags.
template<bool MASK>
__device__ __forceinline__ void attn_stepN(const char* smem, int h, int kt,
                                           s16x8 qfh, int lane,
                                           f32x16& acc, float& lsum) {
  const int half = lane >> 5;
  const int krow = kt * 32 + (lane & 31);
  s16x8 kf = *(const s16x8*)(smem + BUF0 + krow * 256 +
                             swzk(krow, h * 32 + half * 16));
  f32x16 st = __builtin_amdgcn_mfma_f32_32x32x16_bf16(kf, qfh, (f32x16){}, 0, 0, 0);
  const int vrow = h * 16 + (lane & 15);
  s16x8 vf0 = *(const s16x8*)(smem + VOFF + vrow * 512 +
                              swz(vrow, kt * 64 + half * 16));
  s16x8 vf1 = *(const s16x8*)(smem + VOFF + vrow * 512 +
                              swz(vrow, kt * 64 + 32 + half * 16));
  const int NR = MASK ? 12 : 16;
  u32 A[8];
  float ts0 = 0.f, ts1 = 0.f;
#pragma unroll
  for (int i = 0; i < 8; ++i) {
    float p0 = (2 * i < NR) ? __builtin_amdgcn_exp2f(st[2 * i]) : 0.f;
    float p1 = (2 * i + 1 < NR) ? __builtin_amdgcn_exp2f(st[2 * i + 1]) : 0.f;
    if (i & 1) ts1 += p0 + p1; else ts0 += p0 + p1;
    A[i] = pack2(p0, p1);
  }
  lsum += ts0 + ts1;
  s16x8 pf0 = __builtin_bit_cast(s16x8, (u32x4v){A[0], A[1], A[2], A[3]});
  s16x8 pf1 = __builtin_bit_cast(s16x8, (u32x4v){A[4], A[5], A[6], A[7]});
  acc = __builtin_amdgcn_mfma_f32_32x32x16_bf16(vf0, pf0, acc, 0, 0, 0);
  acc = __builtin_amdgcn_mfma_f32_32x32x16_bf16(vf1, pf1, acc, 0, 0, 0);
}

// fallback step (all-&7 swizzle, verified r6-r9; setprio also removed -- hint only)
template<bool MASK>
__device__ __forceinline__ void attn_stepF(const char* smem, int h, int kt,
                                           s16x8 qfh, int lane,
                                           f32x16& acc, float& lsum) {
  const int half = lane >> 5;
  const int krow = kt * 32 + (lane & 31);
  s16x8 kf = *(const s16x8*)(smem + BUF0 + krow * 256 +
                             swz(krow, h * 32 + half * 16));
  f32x16 st = __builtin_amdgcn_mfma_f32_32x32x16_bf16(kf, qfh, (f32x16){}, 0, 0, 0);
  const int vrow = h * 16 + (lane & 15);
  s16x8 vf0 = *(const s16x8*)(smem + VOFF + vrow * 512 +
                              swz(vrow, kt * 64 + half * 16));
  s16x8 vf1 = *(const s16x8*)(smem + VOFF + vrow * 512 +
                              swz(vrow, kt * 64 + 32 + half * 16));
  const int NR = MASK ? 12 : 16;
  u32 A[8];
  float ts0 = 0.f, ts1 = 0.f;
#pragma unroll
  for (int i = 0; i < 8; ++i) {
    float p0 = (2 * i < NR) ? __builtin_amdgcn_exp2f(st[2 * i]) : 0.f;
    float p1 = (2 * i + 1 < NR) ? __builtin_amdgcn_exp2f(st[2 * i + 1]) : 0.f;
    if (i & 1) ts1 += p0 + p1; else ts0 += p0 + p1;
    A[i] = pack2(p0, p1);
  }
  lsum += ts0 + ts1;
  s16x8 pf0 = __builtin_bit_cast(s16x8, (u32x4v){A[0], A[1], A[2], A[3]});
  s16x8 pf1 = __builtin_bit_cast(s16x8, (u32x4v){A[4], A[5], A[6], A[7]});
  acc = __builtin_amdgcn_mfma_f32_32x32x16_bf16(vf0, pf0, acc, 0, 0, 0);
  acc = __builtin_amdgcn_mfma_f32_32x32x16_bf16(vf1, pf1, acc, 0, 0, 0);
}

// ================= Kernel 1: LN + layout transform (round-9 version) ========
extern "C" __global__ __launch_bounds__(256)
void lnpre_kernel(const float* __restrict__ qm, const float* __restrict__ km,
                  const float* __restrict__ vm,
                  const float* __restrict__ gq, const float* __restrict__ bq,
                  const float* __restrict__ gkv, const float* __restrict__ bkv,
                  const float* __restrict__ pw,
                  u16* __restrict__ qn, u16* __restrict__ kn,
                  u16* __restrict__ vn, u16* __restrict__ wbf) {
  const int tid = threadIdx.x;
  const int bid = blockIdx.x;
  if (bid >= 2304) {            // W conversion: 16384 f32 -> bf16
#pragma unroll
    for (int k = 0; k < 32; ++k) {
      int idx = tid + 256 * k;
      f32x2 w2 = *(const f32x2*)(pw + idx * 2);
      ((u32*)wbf)[idx] = pack2(w2.x, w2.y);
    }
    return;
  }
  __shared__ float lf[6144];    // [128 ch][48 w] fp32
  __shared__ float gb[512];
  const int d = bid / 48, h = bid - d * 48;
  const int dh = d * 2304 + h * 48;     // global token base of (d,h,0)
  if (tid < 128) {
    gb[tid] = gq[tid]; gb[128 + tid] = bq[tid];
    gb[256 + tid] = gkv[tid]; gb[384 + tid] = bkv[tid];
  }
  const int w = tid >> 2, q = tid & 3;
#pragma unroll 1
  for (int t = 0; t < 3; ++t) {
    const float* src = t == 0 ? qm : (t == 1 ? km : vm);
    u16* dst = t == 0 ? qn : (t == 1 ? kn : vn);
    const float* g = (t == 0) ? gb : gb + 256;
    const float* b = (t == 0) ? gb + 128 : gb + 384;
    const float scale = (t == 0) ? QSCALE : 1.0f;
#pragma unroll
    for (int k = 0; k < 6; ++k) {       // 24KB coalesced load
      int j = tid + 256 * k;
      int ch = j / 12, wq = j - ch * 12;
      *(f32x4*)(lf + ch * 48 + wq * 4) =
          *(const f32x4*)(src + (long)ch * SP + dh + wq * 4);
    }
    __syncthreads();
    if (tid < 192) {                    // thread (w, q): LN of token (d,h,w)
      float s = 0.f, s2 = 0.f;
#pragma unroll
      for (int c = 0; c < 32; ++c) {
        float x = lf[(q + 4 * c) * 48 + w];
        s += x; s2 += x * x;
      }
      s += __shfl_xor(s, 1); s2 += __shfl_xor(s2, 1);
      s += __shfl_xor(s, 2); s2 += __shfl_xor(s2, 2);
      float m = s * (1.f / 128.f);
      float r = rsqrtf(s2 * (1.f / 128.f) - m * m + 1e-5f);
      u32x4v* op = (u32x4v*)(dst + (long)(dh + w) * 128 + 32 * q);
#pragma unroll
      for (int v4 = 0; v4 < 4; ++v4) {
        u32x4v pk;
#pragma unroll
        for (int e = 0; e < 4; ++e) {
          int ch = 32 * q + v4 * 8 + 2 * e;
          float y0 = ((lf[ch * 48 + w] - m) * r * g[ch] + b[ch]) * scale;
          float y1 = ((lf[(ch + 1) * 48 + w] - m) * r * g[ch + 1] + b[ch + 1]) * scale;
          pk[e] = pack2(y0, y1);
        }
        op[v4] = pk;
      }
    }
    __syncthreads();
  }
}

// ================= Kernel 2: attention + projection =========================
// 14 waves: waves 0-6 = heads 0-3, waves 7-13 = heads 4-7. No setprio fences;
// K/W/obuf tiles on swzk (&15).
extern "C" __global__ __launch_bounds__(T2, 1)
void attn2_kernel(const u16* __restrict__ qn, const u16* __restrict__ kn,
                  const u16* __restrict__ vn, const u16* __restrict__ wbf,
                  const float* __restrict__ pb, float* __restrict__ out) {
  extern __shared__ __align__(16) char smem[];
  const int tid = threadIdx.x;
  const int lane = tid & 63;
  const int wv = tid >> 6;          // 0..13
  const int wq = wv % 7;            // q-row group
  const int hb = (wv / 7) * 4;      // head base for this wavegroup
  const int bid = blockIdx.x;
  const int wid = ((bid & 7) << 6) | (bid >> 3);   // XCD chunked swizzle
  const int wd = wid >> 6, wh = (wid >> 3) & 7, ww = wid & 7;
  const int wd6 = wd * 6, wh6 = wh * 6, ww6 = ww * 6;
  const int boff = wd6 * 2304 + wh6 * 48 + ww6;

  // P1: stage Q (swzk-src) -> BUF0, Vraw (linear) -> VOFF, W (swzk-src) -> WOFF
  for (int uu = wv; uu < 140; uu += 14) {
    const u16* s; char* d;
    if (uu < 54) {
      int u = uu, row = 4 * u + (lane >> 4);
      int tq = row / 6;
      int g = (wd6 + tq / 6) * 2304 + (wh6 + tq % 6) * 48 + ww6 + row % 6;
      s = qn + g * 128 + (((lane & 15) ^ (row & 15)) << 3);
      d = smem + BUF0 + u * 1024;
    } else if (uu < 108) {
      int u = uu - 54, row = 4 * u + (lane >> 4);
      int tq = row / 6;
      int g = (wd6 + tq / 6) * 2304 + (wh6 + tq % 6) * 48 + ww6 + row % 6;
      s = vn + g * 128 + ((lane & 15) << 3);
      d = smem + VOFF + u * 1024;
    } else {
      int u = uu - 108, row = 4 * u + (lane >> 4);
      s = wbf + row * 128 + (((lane & 15) ^ (row & 15)) << 3);
      d = smem + WOFF + u * 1024;
    }
    gload16(s, d);
  }
  __syncthreads();

  // P2: Q fragments for this wavegroup's 4 heads
  s16x8 qf[4];
  {
    int row = wq * 32 + (lane & 31);
    int ib = (lane >> 5) * 16;
#pragma unroll
    for (int j = 0; j < 4; ++j)
      qf[j] = *(const s16x8*)(smem + BUF0 + row * 256 +
                              swzk(row, (hb + j) * 32 + ib));
  }
  __syncthreads();

  // P3: stage K -> BUF0 (overwrite Q); read Vraw -> regs
  for (int uu = wv; uu < 54; uu += 14) {
    int row = 4 * uu + (lane >> 4);
    int tq = row / 6;
    int g = (wd6 + tq / 6) * 2304 + (wh6 + tq % 6) * 48 + ww6 + row % 6;
    gload16(kn + g * 128 + (((lane & 15) ^ (row & 15)) << 3),
            smem + BUF0 + uu * 1024);
  }
  u32 tr[16];
#pragma unroll
  for (int k = 0; k < 8; ++k) {
    int u = tid + 896 * k;
    if (u < 6912) {
      int t = (u >> 6) * 2, c2 = u & 63;
      tr[2 * k]     = *(const u32*)(smem + VOFF + t * 256 + c2 * 4);
      tr[2 * k + 1] = *(const u32*)(smem + VOFF + t * 256 + 256 + c2 * 4);
    }
  }
  __syncthreads();

  // P4: write Vt [ch][sigma(tok)] swizzled (&7); zero read-but-unwritten pads
#pragma unroll
  for (int k = 0; k < 8; ++k) {
    int u = tid + 896 * k;
    if (u < 6912) {
      int t = (u >> 6) * 2, c2 = u & 63;
      int st = (t & ~12) | ((t & 4) << 1) | ((t & 8) >> 1);  // sigma(t), even
      int c = 2 * c2;
      u32 w0 = (tr[2 * k] & 0xFFFFu) | (tr[2 * k + 1] << 16);
      u32 w1 = (tr[2 * k] >> 16) | (tr[2 * k + 1] & 0xFFFF0000u);
      *(u32*)(smem + VOFF + c * 512 + ((st * 2) ^ ((c & 7) << 4))) = w0;
      *(u32*)(smem + VOFF + (c + 1) * 512 + ((st * 2) ^ (((c + 1) & 7) << 4))) = w1;
    }
  }
  if (tid < 128) {   // pad slots: sigma-positions {212-215,220-223}
    int x = (tid & 7) << 4;
    *(u32*)(smem + VOFF + tid * 512 + (424 ^ x)) = 0;
    *(u32*)(smem + VOFF + tid * 512 + (428 ^ x)) = 0;
    *(u32*)(smem + VOFF + tid * 512 + (440 ^ x)) = 0;
    *(u32*)(smem + VOFF + tid * 512 + (444 ^ x)) = 0;
  }
  __syncthreads();

  // P5: attention -- 2 head-pairs per wave
  u32 oPk[4][4];
#pragma unroll
  for (int hp = 0; hp < 2; ++hp) {
    const int h0 = hb + 2 * hp, h1 = h0 + 1;
    f32x16 a0 = {}, a1 = {};
    float l0 = 0.f, l1 = 0.f;
#pragma unroll 2
    for (int kt = 0; kt < 6; ++kt) {
      attn_stepN<false>(smem, h0, kt, qf[2 * hp], lane, a0, l0);
      attn_stepN<false>(smem, h1, kt, qf[2 * hp + 1], lane, a1, l1);
    }
    attn_stepN<true>(smem, h0, 6, qf[2 * hp], lane, a0, l0);
    attn_stepN<true>(smem, h1, 6, qf[2 * hp + 1], lane, a1, l1);
    l0 += __shfl_xor(l0, 32);
    l1 += __shfl_xor(l1, 32);
    float i0 = 1.0f / l0, i1 = 1.0f / l1;
#pragma unroll
    for (int r = 0; r < 4; ++r) {
      oPk[2 * hp][r]     = pack2(a0[2 * r] * i0, a0[2 * r + 1] * i0);
      oPk[2 * hp + 1][r] = pack2(a1[2 * r] * i1, a1[2 * r + 1] * i1);
    }
  }
  __syncthreads();

  // P6: O^T regs -> obuf (BUF0, swzk) [token][ch] bf16
  {
    const int tok = wq * 32 + (lane & 31);
    const int half = lane >> 5;
#pragma unroll
    for (int j = 0; j < 4; ++j) {
      int chb = (hb + j) * 32 + half * 8;
      *(u32*)(smem + BUF0 + tok * 256 + swzk(tok, chb))      = oPk[j][0];
      *(u32*)(smem + BUF0 + tok * 256 + swzk(tok, chb + 4))  = oPk[j][1];
      *(u32*)(smem + BUF0 + tok * 256 + swzk(tok, chb + 16)) = oPk[j][2];
      *(u32*)(smem + BUF0 + tok * 256 + swzk(tok, chb + 20)) = oPk[j][3];
    }
  }
  __syncthreads();

  // P7: projection: D[j][token] = W(A) x O(B); wave owns 1 token tile
  {
    int tok = wv * 16 + (lane & 15);
    s16x8 bfr[4];
#pragma unroll
    for (int kk = 0; kk < 4; ++kk)
      bfr[kk] = *(const s16x8*)(smem + BUF0 + tok * 256 +
                                swzk(tok, kk * 64 + (lane >> 4) * 16));
    bool tokValid = tok < TOK;
    int tdd = tok / 36, trr = tok - tdd * 36;
    int thh = trr / 6, tww = trr - thh * 6;
    int pos = boff + tdd * 2304 + thh * 48 + tww;
#pragma unroll 1
    for (int jt = 0; jt < 8; ++jt) {
      f32x4 acc = {};
#pragma unroll
      for (int kk = 0; kk < 4; ++kk) {
        int rw = jt * 16 + (lane & 15);
        s16x8 af = *(const s16x8*)(smem + WOFF + rw * 256 +
                                   swzk(rw, kk * 64 + (lane >> 4) * 16));
        acc = __builtin_amdgcn_mfma_f32_16x16x32_bf16(af, bfr[kk], acc, 0, 0, 0);
      }
      f32x4 pbv = *(const f32x4*)(pb + jt * 16 + (lane >> 4) * 4);
      if (tokValid) {
#pragma unroll
        for (int r = 0; r < 4; ++r) {
          int j = jt * 16 + (lane >> 4) * 4 + r;
          out[j * SP + pos] = acc[r] + pbv[r];
        }
      }
    }
  }
}

// ================= Fallback: fused single kernel (r7/r9 verified, &7) =======
extern "C" __global__ __launch_bounds__(T1, 2)
void ca3d_kernel(const float* __restrict__ qm, const float* __restrict__ km,
                 const float* __restrict__ vm,
                 const float* __restrict__ gq, const float* __restrict__ bq,
                 const float* __restrict__ gkv, const float* __restrict__ bkv,
                 const float* __restrict__ pw, const float* __restrict__ pb,
                 float* __restrict__ out) {
  extern __shared__ __align__(16) char smem[];
  const int tid = threadIdx.x;
  const int lane = tid & 63;
  const int wv = tid >> 6;
  const int bid = blockIdx.x;
  const int wid = ((bid & 7) << 6) | (bid >> 3);
  const int wd = wid >> 6, wh = (wid >> 3) & 7, ww = wid & 7;
  const int boff = wd * 6 * 2304 + wh * 6 * 48 + ww * 6;

  for (int i = tid * 16; i < VOFF + 65536; i += T1 * 16)
    *(f32x4*)(smem + i) = (f32x4){};
  if (tid < 128) {
    ((float*)(smem + GBOFF))[tid] = gq[tid];
    ((float*)(smem + GBOFF + 512))[tid] = bq[tid];
    ((float*)(smem + GBOFF + 1024))[tid] = gkv[tid];
    ((float*)(smem + GBOFF + 1536))[tid] = bkv[tid];
  }
  const bool lnAct = tid < 432;
  const int tp = tid >> 2;
  const int cbase = (tid & 3) * 32;
  const int tA = tp * 2, tB = tA + 1;
  int td = tA / 36, tr_ = tA - td * 36;
  int th_ = tr_ / 6, tw_ = tr_ - th_ * 6;
  const int gpos = boff + td * 2304 + th_ * 48 + tw_;
  const int vposA = (tA & ~0xC) | ((tA & 4) << 1) | ((tA & 8) >> 1);

  f32x2 qv[32], kv[32], vv[32];
  if (lnAct) {
#pragma unroll
    for (int c = 0; c < 32; ++c)
      qv[c] = *(const f32x2*)(qm + gpos + (cbase + c) * SP);
#pragma unroll
    for (int c = 0; c < 32; ++c)
      kv[c] = *(const f32x2*)(km + gpos + (cbase + c) * SP);
  }
  __syncthreads();
  const float* gql = (const float*)(smem + GBOFF);
  const float* bql = (const float*)(smem + GBOFF + 512);
  const float* gkl = (const float*)(smem + GBOFF + 1024);
  const float* bkl = (const float*)(smem + GBOFF + 1536);
  if (lnAct) {
    float mA, rA, mB, rB;
    ln_stats(qv, mA, rA, mB, rB);
#pragma unroll
    for (int c = 0; c < 32; c += 2) {
      int cc = cbase + c;
      float g0 = gql[cc], g1 = gql[cc + 1], b0 = bql[cc], b1 = bql[cc + 1];
      *(u32*)(smem + BUF0 + tA * 256 + swz(tA, cc * 2)) =
          pack2(((qv[c].x - mA) * rA * g0 + b0) * QSCALE,
                ((qv[c + 1].x - mA) * rA * g1 + b1) * QSCALE);
      *(u32*)(smem + BUF0 + tB * 256 + swz(tB, cc * 2)) =
          pack2(((qv[c].y - mB) * rB * g0 + b0) * QSCALE,
                ((qv[c + 1].y - mB) * rB * g1 + b1) * QSCALE);
    }
#pragma unroll
    for (int c = 0; c < 32; ++c)
      vv[c] = *(const f32x2*)(vm + gpos + (cbase + c) * SP);
  }
  __syncthreads();
  s16x8 qf[8];
  {
    int row = wv * 32 + (lane & 31);
    int ib = (lane >> 5) * 16;
#pragma unroll
    for (int h = 0; h < 8; ++h)
      qf[h] = *(const s16x8*)(smem + BUF0 + row * 256 + swz(row, h * 32 + ib));
  }
  __syncthreads();
  if (lnAct) {
    {
      float mA, rA, mB, rB;
      ln_stats(kv, mA, rA, mB, rB);
#pragma unroll
      for (int c = 0; c < 32; c += 2) {
        int cc = cbase + c;
        float g0 = gkl[cc], g1 = gkl[cc + 1], b0 = bkl[cc], b1 = bkl[cc + 1];
        *(u32*)(smem + BUF0 + tA * 256 + swz(tA, cc * 2)) =
            pack2((kv[c].x - mA) * rA * g0 + b0,
                  (kv[c + 1].x - mA) * rA * g1 + b1);
        *(u32*)(smem + BUF0 + tB * 256 + swz(tB, cc * 2)) =
            pack2((kv[c].y - mB) * rB * g0 + b0,
                  (kv[c + 1].y - mB) * rB * g1 + b1);
      }
    }
    {
      float mA, rA, mB, rB;
      ln_stats(vv, mA, rA, mB, rB);
#pragma unroll
      for (int c = 0; c < 32; ++c) {
        int cc = cbase + c;
        float g0 = gkl[cc], b0 = bkl[cc];
        *(u32*)(smem + VOFF + cc * 512 + swz(cc, vposA * 2)) =
            pack2((vv[c].x - mA) * rA * g0 + b0,
                  (vv[c].y - mB) * rB * g0 + b0);
      }
    }
  }
  for (int i = tid; i < 8192; i += T1) {
    int j = i >> 6, c2 = i & 63;
    f32x2 w2 = *(const f32x2*)(pw + j * 128 + c2 * 2);
    *(u32*)(smem + WOFF + j * 256 + swz(j, c2 * 4)) = pack2(w2.x, w2.y);
  }
  __syncthreads();
  u32 oPk[8][4];
#pragma unroll
  for (int hp = 0; hp < 4; ++hp) {
    const int h0 = hp * 2, h1 = h0 + 1;
    f32x16 a0 = {}, a1 = {};
    float l0 = 0.f, l1 = 0.f;
#pragma unroll 1
    for (int kt = 0; kt < 6; ++kt) {
      attn_stepF<false>(smem, h0, kt, qf[h0], lane, a0, l0);
      attn_stepF<false>(smem, h1, kt, qf[h1], lane, a1, l1);
    }
    attn_stepF<true>(smem, h0, 6, qf[h0], lane, a0, l0);
    attn_stepF<true>(smem, h1, 6, qf[h1], lane, a1, l1);
    l0 += __shfl_xor(l0, 32);
    l1 += __shfl_xor(l1, 32);
    float i0 = 1.0f / l0, i1 = 1.0f / l1;
#pragma unroll
    for (int r = 0; r < 4; ++r) {
      oPk[h0][r] = pack2(a0[2 * r] * i0, a0[2 * r + 1] * i0);
      oPk[h1][r] = pack2(a1[2 * r] * i1, a1[2 * r + 1] * i1);
    }
  }
  __syncthreads();
  {
    const int tok = wv * 32 + (lane & 31);
    const int half = lane >> 5;
#pragma unroll
    for (int h = 0; h < 8; ++h) {
      int chb = h * 32 + half * 8;
      *(u32*)(smem + BUF0 + tok * 256 + swz(tok, chb))      = oPk[h][0];
      *(u32*)(smem + BUF0 + tok * 256 + swz(tok, chb + 4))  = oPk[h][1];
      *(u32*)(smem + BUF0 + tok * 256 + swz(tok, chb + 16)) = oPk[h][2];
      *(u32*)(smem + BUF0 + tok * 256 + swz(tok, chb + 20)) = oPk[h][3];
    }
  }
  __syncthreads();
#pragma unroll 1
  for (int ti = 0; ti < 2; ++ti) {
    int tt = wv * 2 + ti;
    int tok = tt * 16 + (lane & 15);
    s16x8 bfr[4];
#pragma unroll
    for (int kk = 0; kk < 4; ++kk)
      bfr[kk] = *(const s16x8*)(smem + BUF0 + tok * 256 +
                                swz(tok, kk * 64 + (lane >> 4) * 16));
    bool tokValid = tok < TOK;
    int tdd = tok / 36, trr = tok - tdd * 36;
    int thh = trr / 6, tww = trr - thh * 6;
    int pos = boff + tdd * 2304 + thh * 48 + tww;
#pragma unroll 1
    for (int jt = 0; jt < 8; ++jt) {
      f32x4 acc = {};
#pragma unroll
      for (int kk = 0; kk < 4; ++kk) {
        int rw = jt * 16 + (lane & 15);
        s16x8 af = *(const s16x8*)(smem + WOFF + rw * 256 +
                                   swz(rw, kk * 64 + (lane >> 4) * 16));
        acc = __builtin_amdgcn_mfma_f32_16x16x32_bf16(af, bfr[kk], acc, 0, 0, 0);
      }
      f32x4 pbv = *(const f32x4*)(pb + jt * 16 + (lane >> 4) * 4);
      if (tokValid) {
#pragma unroll
        for (int r = 0; r < 4; ++r) {
          int j = jt * 16 + (lane >> 4) * 4 + r;
          out[j * SP + pos] = acc[r] + pbv[r];
        }
      }
    }
  }
}

extern "C" void kernel_launch(void* const* d_in, const int* in_sizes, int n_in,
                              void* d_out, int out_size, void* d_ws, size_t ws_size,
                              hipStream_t stream) {
  const float* qm  = (const float*)d_in[0];
  const float* km  = (const float*)d_in[1];
  const float* vm  = (const float*)d_in[2];
  const float* gq  = (const float*)d_in[3];
  const float* bq  = (const float*)d_in[4];
  const float* gkv = (const float*)d_in[5];
  const float* bkv = (const float*)d_in[6];
  const float* pw  = (const float*)d_in[7];
  const float* pb  = (const float*)d_in[8];
  if (ws_size >= WSNEED) {
    u16* qn  = (u16*)d_ws;
    u16* kn  = (u16*)((char*)d_ws + TENB);
    u16* vn  = (u16*)((char*)d_ws + 2 * TENB);
    u16* wbf = (u16*)((char*)d_ws + 3 * TENB);
    hipLaunchKernelGGL(lnpre_kernel, dim3(2305), dim3(256), 0, stream,
                       qm, km, vm, gq, bq, gkv, bkv, pw, qn, kn, vn, wbf);
    hipLaunchKernelGGL(attn2_kernel, dim3(512), dim3(T2), LDS_NEW, stream,
                       qn, kn, vn, wbf, pb, (float*)d_out);
  } else {
    hipLaunchKernelGGL(ca3d_kernel, dim3(512), dim3(T1), LDS_OLD, stream,
                       qm, km, vm, gq, bq, gkv, bkv, pw, pb, (float*)d_out);
  }
}

// Round 12
// 139.631 us; speedup vs baseline: 1.6602x; 1.0737x over previous
//
#include <hip/hip_runtime.h>
#include <hip/hip_bf16.h>

typedef short s16x8 __attribute__((ext_vector_type(8)));
typedef float f32x2 __attribute__((ext_vector_type(2)));
typedef float f32x4 __attribute__((ext_vector_type(4)));
typedef float f32x16 __attribute__((ext_vector_type(16)));
typedef unsigned int u32;
typedef unsigned short u16;
typedef u32 u32x4v __attribute__((ext_vector_type(4)));

#define TOK 216
#define T1 448
#define SP 110592
// fallback LDS map
#define BUF0 0
#define VOFF 57344
#define WOFF 122880
#define GBOFF 155648
#define LDS_OLD 157696
// attnh LDS map: KH [224 rows x 128B] then obuf; VHOFF Vraw(27KB)->Vt 64x512B
#define VHOFF 28672
#define TENB 28311552ull
#define WSNEED (3ull*TENB + 32768ull)
#define QSCALE 0.360673760f // 0.25 * log2(e): scores*log2e -> exp2

__device__ __forceinline__ u32 pack2(float a, float b) {
  u16 lo = __builtin_bit_cast(u16, __float2bfloat16(a));
  u16 hi = __builtin_bit_cast(u16, __float2bfloat16(b));
  return (u32)lo | ((u32)hi << 16);
}
__device__ __forceinline__ int swz(int row, int inner) {
  return inner ^ ((row & 7) << 4);
}
__device__ __forceinline__ void gload16(const void* g, void* l) {
  __builtin_amdgcn_global_load_lds(
      (const __attribute__((address_space(1))) void*)g,
      (__attribute__((address_space(3))) void*)l, 16, 0, 0);
}

__device__ __forceinline__ void ln_stats(const f32x2* xv, float& mA, float& rA,
                                         float& mB, float& rB) {
  float sA = 0.f, s2A = 0.f, sB = 0.f, s2B = 0.f;
#pragma unroll
  for (int c = 0; c < 32; ++c) {
    sA += xv[c].x; s2A += xv[c].x * xv[c].x;
    sB += xv[c].y; s2B += xv[c].y * xv[c].y;
  }
  sA += __shfl_xor(sA, 1); s2A += __shfl_xor(s2A, 1);
  sB += __shfl_xor(sB, 1); s2B += __shfl_xor(s2B, 1);
  sA += __shfl_xor(sA, 2); s2A += __shfl_xor(s2A, 2);
  sB += __shfl_xor(sB, 2); s2B += __shfl_xor(s2B, 2);
  mA = sA * (1.0f / 128.0f);
  rA = rsqrtf(s2A * (1.0f / 128.0f) - mA * mA + 1e-5f);
  mB = sB * (1.0f / 128.0f);
  rB = rsqrtf(s2B * (1.0f / 128.0f) - mB * mB + 1e-5f);
}

// attnh step: head-half tiles (K rows 128B, V-half 64 ch-rows). Verified
// r6-r11 math with half-width indexing. No-max softmax (exp2, log2e in Q);
// sigma-permuted V so packed P regs ARE the PV B-fragments.
template<bool MASK>
__device__ __forceinline__ void attn_stepH(const char* smem, int jloc, int kt,
                                           s16x8 qfh, int lane,
                                           f32x16& acc, float& lsum) {
  const int half = lane >> 5;
  const int krow = kt * 32 + (lane & 31);
  s16x8 kf = *(const s16x8*)(smem + krow * 128 +
                             ((jloc * 32 + half * 16) ^ ((krow & 7) << 4)));
  f32x16 st = __builtin_amdgcn_mfma_f32_32x32x16_bf16(kf, qfh, (f32x16){}, 0, 0, 0);
  const int vrow = jloc * 16 + (lane & 15);
  s16x8 vf0 = *(const s16x8*)(smem + VHOFF + vrow * 512 +
                              ((kt * 64 + half * 16) ^ ((vrow & 7) << 4)));
  s16x8 vf1 = *(const s16x8*)(smem + VHOFF + vrow * 512 +
                              ((kt * 64 + 32 + half * 16) ^ ((vrow & 7) << 4)));
  const int NR = MASK ? 12 : 16;
  u32 A[8];
  float ts0 = 0.f, ts1 = 0.f;
#pragma unroll
  for (int i = 0; i < 8; ++i) {
    float p0 = (2 * i < NR) ? __builtin_amdgcn_exp2f(st[2 * i]) : 0.f;
    float p1 = (2 * i + 1 < NR) ? __builtin_amdgcn_exp2f(st[2 * i + 1]) : 0.f;
    if (i & 1) ts1 += p0 + p1; else ts0 += p0 + p1;
    A[i] = pack2(p0, p1);
  }
  lsum += ts0 + ts1;
  s16x8 pf0 = __builtin_bit_cast(s16x8, (u32x4v){A[0], A[1], A[2], A[3]});
  s16x8 pf1 = __builtin_bit_cast(s16x8, (u32x4v){A[4], A[5], A[6], A[7]});
  acc = __builtin_amdgcn_mfma_f32_32x32x16_bf16(vf0, pf0, acc, 0, 0, 0);
  acc = __builtin_amdgcn_mfma_f32_32x32x16_bf16(vf1, pf1, acc, 0, 0, 0);
}

// fallback step (verified r6-r11)
template<bool MASK>
__device__ __forceinline__ void attn_stepF(const char* smem, int h, int kt,
                                           s16x8 qfh, int lane,
                                           f32x16& acc, float& lsum) {
  const int half = lane >> 5;
  const int krow = kt * 32 + (lane & 31);
  s16x8 kf = *(const s16x8*)(smem + BUF0 + krow * 256 +
                             swz(krow, h * 32 + half * 16));
  f32x16 st = __builtin_amdgcn_mfma_f32_32x32x16_bf16(kf, qfh, (f32x16){}, 0, 0, 0);
  const int vrow = h * 16 + (lane & 15);
  s16x8 vf0 = *(const s16x8*)(smem + VOFF + vrow * 512 +
                              swz(vrow, kt * 64 + half * 16));
  s16x8 vf1 = *(const s16x8*)(smem + VOFF + vrow * 512 +
                              swz(vrow, kt * 64 + 32 + half * 16));
  const int NR = MASK ? 12 : 16;
  u32 A[8];
  float ts0 = 0.f, ts1 = 0.f;
#pragma unroll
  for (int i = 0; i < 8; ++i) {
    float p0 = (2 * i < NR) ? __builtin_amdgcn_exp2f(st[2 * i]) : 0.f;
    float p1 = (2 * i + 1 < NR) ? __builtin_amdgcn_exp2f(st[2 * i + 1]) : 0.f;
    if (i & 1) ts1 += p0 + p1; else ts0 += p0 + p1;
    A[i] = pack2(p0, p1);
  }
  lsum += ts0 + ts1;
  s16x8 pf0 = __builtin_bit_cast(s16x8, (u32x4v){A[0], A[1], A[2], A[3]});
  s16x8 pf1 = __builtin_bit_cast(s16x8, (u32x4v){A[4], A[5], A[6], A[7]});
  acc = __builtin_amdgcn_mfma_f32_32x32x16_bf16(vf0, pf0, acc, 0, 0, 0);
  acc = __builtin_amdgcn_mfma_f32_32x32x16_bf16(vf1, pf1, acc, 0, 0, 0);
}

// ================= Kernel 1: LN + layout transform (r9/r11 verified) ========
extern "C" __global__ __launch_bounds__(256)
void lnpre_kernel(const float* __restrict__ qm, const float* __restrict__ km,
                  const float* __restrict__ vm,
                  const float* __restrict__ gq, const float* __restrict__ bq,
                  const float* __restrict__ gkv, const float* __restrict__ bkv,
                  const float* __restrict__ pw,
                  u16* __restrict__ qn, u16* __restrict__ kn,
                  u16* __restrict__ vn, u16* __restrict__ wbf) {
  const int tid = threadIdx.x;
  const int bid = blockIdx.x;
  if (bid >= 2304) {
#pragma unroll
    for (int k = 0; k < 32; ++k) {
      int idx = tid + 256 * k;
      f32x2 w2 = *(const f32x2*)(pw + idx * 2);
      ((u32*)wbf)[idx] = pack2(w2.x, w2.y);
    }
    return;
  }
  __shared__ float lf[6144];
  __shared__ float gb[512];
  const int d = bid / 48, h = bid - d * 48;
  const int dh = d * 2304 + h * 48;
  if (tid < 128) {
    gb[tid] = gq[tid]; gb[128 + tid] = bq[tid];
    gb[256 + tid] = gkv[tid]; gb[384 + tid] = bkv[tid];
  }
  const int w = tid >> 2, q = tid & 3;
#pragma unroll 1
  for (int t = 0; t < 3; ++t) {
    const float* src = t == 0 ? qm : (t == 1 ? km : vm);
    u16* dst = t == 0 ? qn : (t == 1 ? kn : vn);
    const float* g = (t == 0) ? gb : gb + 256;
    const float* b = (t == 0) ? gb + 128 : gb + 384;
    const float scale = (t == 0) ? QSCALE : 1.0f;
#pragma unroll
    for (int k = 0; k < 6; ++k) {
      int j = tid + 256 * k;
      int ch = j / 12, wq = j - ch * 12;
      *(f32x4*)(lf + ch * 48 + wq * 4) =
          *(const f32x4*)(src + (long)ch * SP + dh + wq * 4);
    }
    __syncthreads();
    if (tid < 192) {
      float s = 0.f, s2 = 0.f;
#pragma unroll
      for (int c = 0; c < 32; ++c) {
        float x = lf[(q + 4 * c) * 48 + w];
        s += x; s2 += x * x;
      }
      s += __shfl_xor(s, 1); s2 += __shfl_xor(s2, 1);
      s += __shfl_xor(s, 2); s2 += __shfl_xor(s2, 2);
      float m = s * (1.f / 128.f);
      float r = rsqrtf(s2 * (1.f / 128.f) - m * m + 1e-5f);
      u32x4v* op = (u32x4v*)(dst + (long)(dh + w) * 128 + 32 * q);
#pragma unroll
      for (int v4 = 0; v4 < 4; ++v4) {
        u32x4v pk;
#pragma unroll
        for (int e = 0; e < 4; ++e) {
          int ch = 32 * q + v4 * 8 + 2 * e;
          float y0 = ((lf[ch * 48 + w] - m) * r * g[ch] + b[ch]) * scale;
          float y1 = ((lf[(ch + 1) * 48 + w] - m) * r * g[ch + 1] + b[ch + 1]) * scale;
          pk[e] = pack2(y0, y1);
        }
        op[v4] = pk;
      }
    }
    __syncthreads();
  }
}

// ================= Kernel 2: attention, (window x head-half) blocks =========
// 1024 blocks x 448 threads, 61440B LDS -> 2 blocks/CU. O-half streamed
// coalesced into qn in-place (block only overwrites rows/bytes only it reads).
extern "C" __global__ __launch_bounds__(448, 4)
void attnh_kernel(u16* __restrict__ qn, const u16* __restrict__ kn,
                  const u16* __restrict__ vn) {
  __shared__ __align__(16) char smem[61440];
  const int tid = threadIdx.x, lane = tid & 63, wv = tid >> 6;
  const int half = lane >> 5;
  const int bid = blockIdx.x;
  const int wid = bid >> 1, hg = bid & 1;
  const int wd6 = (wid >> 6) * 6, wh6 = ((wid >> 3) & 7) * 6, ww6 = (wid & 7) * 6;

  // stage K-half (swz-src, 8 rows x 128B per unit)
  for (int uu = wv; uu < 27; uu += 7) {
    int row = 8 * uu + (lane >> 3);
    int tq = row / 6;
    int g = (wd6 + tq / 6) * 2304 + (wh6 + tq % 6) * 48 + ww6 + row % 6;
    gload16(kn + g * 128 + hg * 64 + (((lane & 7) ^ (row & 7)) << 3),
            smem + uu * 1024);
  }
  // stage V-half raw (linear rows [tok][64ch])
  for (int uu = wv; uu < 27; uu += 7) {
    int row = 8 * uu + (lane >> 3);
    int tq = row / 6;
    int g = (wd6 + tq / 6) * 2304 + (wh6 + tq % 6) * 48 + ww6 + row % 6;
    gload16(vn + g * 128 + hg * 64 + ((lane & 7) << 3),
            smem + VHOFF + uu * 1024);
  }
  // Q fragments direct from global (drain overlaps K/V staging)
  int qrow = wv * 32 + (lane & 31);
  if (qrow > 215) qrow = 215;
  int qtq = qrow / 6;
  int qg = (wd6 + qtq / 6) * 2304 + (wh6 + qtq % 6) * 48 + ww6 + qrow % 6;
  s16x8 qf[4];
#pragma unroll
  for (int j = 0; j < 4; ++j)
    qf[j] = *(const s16x8*)(qn + qg * 128 + (hg * 4 + j) * 16 + half * 8);
  __syncthreads();

  // V transpose: Vraw rows 0..215 -> regs -> Vt [64 ch][512B sigma(tok)]
  u32 tr[16];
#pragma unroll
  for (int k = 0; k < 8; ++k) {
    int u = tid + 448 * k;
    if (u < 3456) {
      int t = (u >> 5) * 2, c2 = u & 31;
      tr[2 * k]     = *(const u32*)(smem + VHOFF + t * 128 + c2 * 4);
      tr[2 * k + 1] = *(const u32*)(smem + VHOFF + t * 128 + 128 + c2 * 4);
    }
  }
  __syncthreads();
#pragma unroll
  for (int k = 0; k < 8; ++k) {
    int u = tid + 448 * k;
    if (u < 3456) {
      int t = (u >> 5) * 2, c2 = u & 31;
      int st = (t & ~12) | ((t & 4) << 1) | ((t & 8) >> 1);
      int c = 2 * c2;
      u32 w0 = (tr[2 * k] & 0xFFFFu) | (tr[2 * k + 1] << 16);
      u32 w1 = (tr[2 * k] >> 16) | (tr[2 * k + 1] & 0xFFFF0000u);
      *(u32*)(smem + VHOFF + c * 512 + ((st * 2) ^ ((c & 7) << 4))) = w0;
      *(u32*)(smem + VHOFF + (c + 1) * 512 + ((st * 2) ^ (((c + 1) & 7) << 4))) = w1;
    }
  }
  if (tid < 64) {   // sigma-positions {212-215,220-223} zeroed
    int x = (tid & 7) << 4;
    *(u32*)(smem + VHOFF + tid * 512 + (424 ^ x)) = 0;
    *(u32*)(smem + VHOFF + tid * 512 + (428 ^ x)) = 0;
    *(u32*)(smem + VHOFF + tid * 512 + (440 ^ x)) = 0;
    *(u32*)(smem + VHOFF + tid * 512 + (444 ^ x)) = 0;
  }
  __syncthreads();

  // attention: wave owns q rows [wv*32,+32), 4 heads (2 pairs)
  u32 oPk[4][4];
#pragma unroll
  for (int hp = 0; hp < 2; ++hp) {
    const int j0 = 2 * hp, j1 = j0 + 1;
    f32x16 a0 = {}, a1 = {};
    float l0 = 0.f, l1 = 0.f;
#pragma unroll 2
    for (int kt = 0; kt < 6; ++kt) {
      attn_stepH<false>(smem, j0, kt, qf[j0], lane, a0, l0);
      attn_stepH<false>(smem, j1, kt, qf[j1], lane, a1, l1);
    }
    attn_stepH<true>(smem, j0, 6, qf[j0], lane, a0, l0);
    attn_stepH<true>(smem, j1, 6, qf[j1], lane, a1, l1);
    l0 += __shfl_xor(l0, 32);
    l1 += __shfl_xor(l1, 32);
    float i0 = 1.0f / l0, i1 = 1.0f / l1;
#pragma unroll
    for (int r = 0; r < 4; ++r) {
      oPk[j0][r] = pack2(a0[2 * r] * i0, a0[2 * r + 1] * i0);
      oPk[j1][r] = pack2(a1[2 * r] * i1, a1[2 * r + 1] * i1);
    }
  }
  __syncthreads();   // all K reads done; reuse KH region as obuf

  // obuf: O^T regs -> [tok][128B half-row]
  {
    const int tok = wv * 32 + (lane & 31);
#pragma unroll
    for (int j = 0; j < 4; ++j) {
      int chb = j * 32 + half * 8;
      *(u32*)(smem + tok * 128 + ((chb)      ^ ((tok & 7) << 4))) = oPk[j][0];
      *(u32*)(smem + tok * 128 + ((chb + 4)  ^ ((tok & 7) << 4))) = oPk[j][1];
      *(u32*)(smem + tok * 128 + ((chb + 16) ^ ((tok & 7) << 4))) = oPk[j][2];
      *(u32*)(smem + tok * 128 + ((chb + 20) ^ ((tok & 7) << 4))) = oPk[j][3];
    }
  }
  __syncthreads();

  // stream obuf -> qn (in-place O-half; coalesced 128B pieces)
#pragma unroll
  for (int it = 0; it < 4; ++it) {
    int i = tid + 448 * it;
    int row = i >> 3;
    if (row < 216) {
      int chunk = i & 7;
      f32x4 v = *(const f32x4*)(smem + row * 128 +
                                ((chunk * 16) ^ ((row & 7) << 4)));
      int tq = row / 6;
      int g = (wd6 + tq / 6) * 2304 + (wh6 + tq % 6) * 48 + ww6 + row % 6;
      *(f32x4*)(qn + g * 128 + hg * 64 + chunk * 8) = v;
    }
  }
}

// ================= Kernel 3: projection GEMM + unwindow =====================
// 2304 (d,h)-line blocks x 256 threads. O rows token-contiguous from qn;
// out written in 16-consecutive-w runs (no write amplification).
extern "C" __global__ __launch_bounds__(256, 3)
void proj_kernel(const u16* __restrict__ on, const u16* __restrict__ wbf,
                 const float* __restrict__ pb, float* __restrict__ out) {
  __shared__ __align__(16) char smem[45056];   // W 32768 + O 12288
  const int tid = threadIdx.x, lane = tid & 63, wv = tid >> 6;
  const int bid = blockIdx.x;
  const int dh = (bid / 48) * 2304 + (bid % 48) * 48;
  for (int uu = wv; uu < 32; uu += 4) {        // W: 128 rows x 256B
    int row = 4 * uu + (lane >> 4);
    gload16(wbf + row * 128 + (((lane & 15) ^ (row & 15)) << 3),
            smem + uu * 1024);
  }
  for (int uu = wv; uu < 12; uu += 4) {        // O: 48 rows x 256B
    int row = 4 * uu + (lane >> 4);
    gload16(on + (long)(dh + row) * 128 + (((lane & 15) ^ (row & 15)) << 3),
            smem + 32768 + uu * 1024);
  }
  __syncthreads();
#pragma unroll
  for (int jj = 0; jj < 2; ++jj) {
    int jt = wv * 2 + jj;
    int rw = jt * 16 + (lane & 15);
    s16x8 af[4];
#pragma unroll
    for (int kk = 0; kk < 4; ++kk)
      af[kk] = *(const s16x8*)(smem + rw * 256 +
                               ((kk * 64 + (lane >> 4) * 16) ^ ((rw & 15) << 4)));
    f32x4 pbv = *(const f32x4*)(pb + jt * 16 + (lane >> 4) * 4);
#pragma unroll
    for (int t = 0; t < 3; ++t) {
      int tok = t * 16 + (lane & 15);
      f32x4 acc = {};
#pragma unroll
      for (int kk = 0; kk < 4; ++kk) {
        s16x8 bfr = *(const s16x8*)(smem + 32768 + tok * 256 +
                                    ((kk * 64 + (lane >> 4) * 16) ^ ((tok & 15) << 4)));
        acc = __builtin_amdgcn_mfma_f32_16x16x32_bf16(af[kk], bfr, acc, 0, 0, 0);
      }
#pragma unroll
      for (int r = 0; r < 4; ++r) {
        int j = jt * 16 + (lane >> 4) * 4 + r;
        out[(long)j * SP + dh + tok] = acc[r] + pbv[r];
      }
    }
  }
}

// ================= Fallback: fused single kernel (r7-r11 verified) ==========
extern "C" __global__ __launch_bounds__(T1, 2)
void ca3d_kernel(const float* __restrict__ qm, const float* __restrict__ km,
                 const float* __restrict__ vm,
                 const float* __restrict__ gq, const float* __restrict__ bq,
                 const float* __restrict__ gkv, const float* __restrict__ bkv,
                 const float* __restrict__ pw, const float* __restrict__ pb,
                 float* __restrict__ out) {
  extern __shared__ __align__(16) char smem[];
  const int tid = threadIdx.x;
  const int lane = tid & 63;
  const int wv = tid >> 6;
  const int bid = blockIdx.x;
  const int wid = ((bid & 7) << 6) | (bid >> 3);
  const int wd = wid >> 6, wh = (wid >> 3) & 7, ww = wid & 7;
  const int boff = wd * 6 * 2304 + wh * 6 * 48 + ww * 6;

  for (int i = tid * 16; i < VOFF + 65536; i += T1 * 16)
    *(f32x4*)(smem + i) = (f32x4){};
  if (tid < 128) {
    ((float*)(smem + GBOFF))[tid] = gq[tid];
    ((float*)(smem + GBOFF + 512))[tid] = bq[tid];
    ((float*)(smem + GBOFF + 1024))[tid] = gkv[tid];
    ((float*)(smem + GBOFF + 1536))[tid] = bkv[tid];
  }
  const bool lnAct = tid < 432;
  const int tp = tid >> 2;
  const int cbase = (tid & 3) * 32;
  const int tA = tp * 2, tB = tA + 1;
  int td = tA / 36, tr_ = tA - td * 36;
  int th_ = tr_ / 6, tw_ = tr_ - th_ * 6;
  const int gpos = boff + td * 2304 + th_ * 48 + tw_;
  const int vposA = (tA & ~0xC) | ((tA & 4) << 1) | ((tA & 8) >> 1);

  f32x2 qv[32], kv[32], vv[32];
  if (lnAct) {
#pragma unroll
    for (int c = 0; c < 32; ++c)
      qv[c] = *(const f32x2*)(qm + gpos + (cbase + c) * SP);
#pragma unroll
    for (int c = 0; c < 32; ++c)
      kv[c] = *(const f32x2*)(km + gpos + (cbase + c) * SP);
  }
  __syncthreads();
  const float* gql = (const float*)(smem + GBOFF);
  const float* bql = (const float*)(smem + GBOFF + 512);
  const float* gkl = (const float*)(smem + GBOFF + 1024);
  const float* bkl = (const float*)(smem + GBOFF + 1536);
  if (lnAct) {
    float mA, rA, mB, rB;
    ln_stats(qv, mA, rA, mB, rB);
#pragma unroll
    for (int c = 0; c < 32; c += 2) {
      int cc = cbase + c;
      float g0 = gql[cc], g1 = gql[cc + 1], b0 = bql[cc], b1 = bql[cc + 1];
      *(u32*)(smem + BUF0 + tA * 256 + swz(tA, cc * 2)) =
          pack2(((qv[c].x - mA) * rA * g0 + b0) * QSCALE,
                ((qv[c + 1].x - mA) * rA * g1 + b1) * QSCALE);
      *(u32*)(smem + BUF0 + tB * 256 + swz(tB, cc * 2)) =
          pack2(((qv[c].y - mB) * rB * g0 + b0) * QSCALE,
                ((qv[c + 1].y - mB) * rB * g1 + b1) * QSCALE);
    }
#pragma unroll
    for (int c = 0; c < 32; ++c)
      vv[c] = *(const f32x2*)(vm + gpos + (cbase + c) * SP);
  }
  __syncthreads();
  s16x8 qf[8];
  {
    int row = wv * 32 + (lane & 31);
    int ib = (lane >> 5) * 16;
#pragma unroll
    for (int h = 0; h < 8; ++h)
      qf[h] = *(const s16x8*)(smem + BUF0 + row * 256 + swz(row, h * 32 + ib));
  }
  __syncthreads();
  if (lnAct) {
    {
      float mA, rA, mB, rB;
      ln_stats(kv, mA, rA, mB, rB);
#pragma unroll
      for (int c = 0; c < 32; c += 2) {
        int cc = cbase + c;
        float g0 = gkl[cc], g1 = gkl[cc + 1], b0 = bkl[cc], b1 = bkl[cc + 1];
        *(u32*)(smem + BUF0 + tA * 256 + swz(tA, cc * 2)) =
            pack2((kv[c].x - mA) * rA * g0 + b0,
                  (kv[c + 1].x - mA) * rA * g1 + b1);
        *(u32*)(smem + BUF0 + tB * 256 + swz(tB, cc * 2)) =
            pack2((kv[c].y - mB) * rB * g0 + b0,
                  (kv[c + 1].y - mB) * rB * g1 + b1);
      }
    }
    {
      float mA, rA, mB, rB;
      ln_stats(vv, mA, rA, mB, rB);
#pragma unroll
      for (int c = 0; c < 32; ++c) {
        int cc = cbase + c;
        float g0 = gkl[cc], b0 = bkl[cc];
        *(u32*)(smem + VOFF + cc * 512 + swz(cc, vposA * 2)) =
            pack2((vv[c].x - mA) * rA * g0 + b0,
                  (vv[c].y - mB) * rB * g0 + b0);
      }
    }
  }
  for (int i = tid; i < 8192; i += T1) {
    int j = i >> 6, c2 = i & 63;
    f32x2 w2 = *(const f32x2*)(pw + j * 128 + c2 * 2);
    *(u32*)(smem + WOFF + j * 256 + swz(j, c2 * 4)) = pack2(w2.x, w2.y);
  }
  __syncthreads();
  u32 oPk[8][4];
#pragma unroll
  for (int hp = 0; hp < 4; ++hp) {
    const int h0 = hp * 2, h1 = h0 + 1;
    f32x16 a0 = {}, a1 = {};
    float l0 = 0.f, l1 = 0.f;
#pragma unroll 1
    for (int kt = 0; kt < 6; ++kt) {
      attn_stepF<false>(smem, h0, kt, qf[h0], lane, a0, l0);
      attn_stepF<false>(smem, h1, kt, qf[h1], lane, a1, l1);
    }
    attn_stepF<true>(smem, h0, 6, qf[h0], lane, a0, l0);
    attn_stepF<true>(smem, h1, 6, qf[h1], lane, a1, l1);
    l0 += __shfl_xor(l0, 32);
    l1 += __shfl_xor(l1, 32);
    float i0 = 1.0f / l0, i1 = 1.0f / l1;
#pragma unroll
    for (int r = 0; r < 4; ++r) {
      oPk[h0][r] = pack2(a0[2 * r] * i0, a0[2 * r + 1] * i0);
      oPk[h1][r] = pack2(a1[2 * r] * i1, a1[2 * r + 1] * i1);
    }
  }
  __syncthreads();
  {
    const int tok = wv * 32 + (lane & 31);
    const int half = lane >> 5;
#pragma unroll
    for (int h = 0; h < 8; ++h) {
      int chb = h * 32 + half * 8;
      *(u32*)(smem + BUF0 + tok * 256 + swz(tok, chb))      = oPk[h][0];
      *(u32*)(smem + BUF0 + tok * 256 + swz(tok, chb + 4))  = oPk[h][1];
      *(u32*)(smem + BUF0 + tok * 256 + swz(tok, chb + 16)) = oPk[h][2];
      *(u32*)(smem + BUF0 + tok * 256 + swz(tok, chb + 20)) = oPk[h][3];
    }
  }
  __syncthreads();
#pragma unroll 1
  for (int ti = 0; ti < 2; ++ti) {
    int tt = wv * 2 + ti;
    int tok = tt * 16 + (lane & 15);
    s16x8 bfr[4];
#pragma unroll
    for (int kk = 0; kk < 4; ++kk)
      bfr[kk] = *(const s16x8*)(smem + BUF0 + tok * 256 +
                                swz(tok, kk * 64 + (lane >> 4) * 16));
    bool tokValid = tok < TOK;
    int tdd = tok / 36, trr = tok - tdd * 36;
    int thh = trr / 6, tww = trr - thh * 6;
    int pos = boff + tdd * 2304 + thh * 48 + tww;
#pragma unroll 1
    for (int jt = 0; jt < 8; ++jt) {
      f32x4 acc = {};
#pragma unroll
      for (int kk = 0; kk < 4; ++kk) {
        int rw = jt * 16 + (lane & 15);
        s16x8 af = *(const s16x8*)(smem + WOFF + rw * 256 +
                                   swz(rw, kk * 64 + (lane >> 4) * 16));
        acc = __builtin_amdgcn_mfma_f32_16x16x32_bf16(af, bfr[kk], acc, 0, 0, 0);
      }
      f32x4 pbv = *(const f32x4*)(pb + jt * 16 + (lane >> 4) * 4);
      if (tokValid) {
#pragma unroll
        for (int r = 0; r < 4; ++r) {
          int j = jt * 16 + (lane >> 4) * 4 + r;
          out[j * SP + pos] = acc[r] + pbv[r];
        }
      }
    }
  }
}

extern "C" void kernel_launch(void* const* d_in, const int* in_sizes, int n_in,
                              void* d_out, int out_size, void* d_ws, size_t ws_size,
                              hipStream_t stream) {
  const float* qm  = (const float*)d_in[0];
  const float* km  = (const float*)d_in[1];
  const float* vm  = (const float*)d_in[2];
  const float* gq  = (const float*)d_in[3];
  const float* bq  = (const float*)d_in[4];
  const float* gkv = (const float*)d_in[5];
  const float* bkv = (const float*)d_in[6];
  const float* pw  = (const float*)d_in[7];
  const float* pb  = (const float*)d_in[8];
  if (ws_size >= WSNEED) {
    u16* qn  = (u16*)d_ws;                       // Q, then O in-place
    u16* kn  = (u16*)((char*)d_ws + TENB);
    u16* vn  = (u16*)((char*)d_ws + 2 * TENB);
    u16* wbf = (u16*)((char*)d_ws + 3 * TENB);
    hipLaunchKernelGGL(lnpre_kernel, dim3(2305), dim3(256), 0, stream,
                       qm, km, vm, gq, bq, gkv, bkv, pw, qn, kn, vn, wbf);
    hipLaunchKernelGGL(attnh_kernel, dim3(1024), dim3(448), 0, stream,
                       qn, kn, vn);
    hipLaunchKernelGGL(proj_kernel, dim3(2304), dim3(256), 0, stream,
                       qn, wbf, pb, (float*)d_out);
  } else {
    hipLaunchKernelGGL(ca3d_kernel, dim3(512), dim3(T1), LDS_OLD, stream,
                       qm, km, vm, gq, bq, gkv, bkv, pw, pb, (float*)d_out);
  }
}

// Round 13
// 136.965 us; speedup vs baseline: 1.6925x; 1.0195x over previous
//
#include <hip/hip_runtime.h>
#include <hip/hip_bf16.h>

typedef short s16x8 __attribute__((ext_vector_type(8)));
typedef float f32x2 __attribute__((ext_vector_type(2)));
typedef float f32x4 __attribute__((ext_vector_type(4)));
typedef float f32x16 __attribute__((ext_vector_type(16)));
typedef unsigned int u32;
typedef unsigned short u16;
typedef u32 u32x4v __attribute__((ext_vector_type(4)));

#define TOK 216
#define T1 448
#define SP 110592
// fallback LDS map
#define BUF0 0
#define VOFF 57344
#define WOFF 122880
#define GBOFF 155648
#define LDS_OLD 157696
// attnh LDS map: KH [224 rows x 128B] then obuf; VHOFF Vraw(27KB)->Vt 64x512B
#define VHOFF 28672
#define TENB 28311552ull
#define WSNEED (3ull*TENB + 32768ull)
#define QSCALE 0.360673760f // 0.25 * log2(e): scores*log2e -> exp2

__device__ __forceinline__ u32 pack2(float a, float b) {
  u16 lo = __builtin_bit_cast(u16, __float2bfloat16(a));
  u16 hi = __builtin_bit_cast(u16, __float2bfloat16(b));
  return (u32)lo | ((u32)hi << 16);
}
__device__ __forceinline__ int swz(int row, int inner) {
  return inner ^ ((row & 7) << 4);
}
__device__ __forceinline__ void gload16(const void* g, void* l) {
  __builtin_amdgcn_global_load_lds(
      (const __attribute__((address_space(1))) void*)g,
      (__attribute__((address_space(3))) void*)l, 16, 0, 0);
}

__device__ __forceinline__ void ln_stats(const f32x2* xv, float& mA, float& rA,
                                         float& mB, float& rB) {
  float sA = 0.f, s2A = 0.f, sB = 0.f, s2B = 0.f;
#pragma unroll
  for (int c = 0; c < 32; ++c) {
    sA += xv[c].x; s2A += xv[c].x * xv[c].x;
    sB += xv[c].y; s2B += xv[c].y * xv[c].y;
  }
  sA += __shfl_xor(sA, 1); s2A += __shfl_xor(s2A, 1);
  sB += __shfl_xor(sB, 1); s2B += __shfl_xor(s2B, 1);
  sA += __shfl_xor(sA, 2); s2A += __shfl_xor(s2A, 2);
  sB += __shfl_xor(sB, 2); s2B += __shfl_xor(s2B, 2);
  mA = sA * (1.0f / 128.0f);
  rA = rsqrtf(s2A * (1.0f / 128.0f) - mA * mA + 1e-5f);
  mB = sB * (1.0f / 128.0f);
  rB = rsqrtf(s2B * (1.0f / 128.0f) - mB * mB + 1e-5f);
}

// attnh step: head-half tiles (K rows 128B, V-half 64 ch-rows). Verified
// r6-r12 math with half-width indexing. No-max softmax (exp2, log2e in Q);
// sigma-permuted V so packed P regs ARE the PV B-fragments.
template<bool MASK>
__device__ __forceinline__ void attn_stepH(const char* smem, int jloc, int kt,
                                           s16x8 qfh, int lane,
                                           f32x16& acc, float& lsum) {
  const int half = lane >> 5;
  const int krow = kt * 32 + (lane & 31);
  s16x8 kf = *(const s16x8*)(smem + krow * 128 +
                             ((jloc * 32 + half * 16) ^ ((krow & 7) << 4)));
  f32x16 st = __builtin_amdgcn_mfma_f32_32x32x16_bf16(kf, qfh, (f32x16){}, 0, 0, 0);
  const int vrow = jloc * 16 + (lane & 15);
  s16x8 vf0 = *(const s16x8*)(smem + VHOFF + vrow * 512 +
                              ((kt * 64 + half * 16) ^ ((vrow & 7) << 4)));
  s16x8 vf1 = *(const s16x8*)(smem + VHOFF + vrow * 512 +
                              ((kt * 64 + 32 + half * 16) ^ ((vrow & 7) << 4)));
  const int NR = MASK ? 12 : 16;
  u32 A[8];
  float ts0 = 0.f, ts1 = 0.f;
#pragma unroll
  for (int i = 0; i < 8; ++i) {
    float p0 = (2 * i < NR) ? __builtin_amdgcn_exp2f(st[2 * i]) : 0.f;
    float p1 = (2 * i + 1 < NR) ? __builtin_amdgcn_exp2f(st[2 * i + 1]) : 0.f;
    if (i & 1) ts1 += p0 + p1; else ts0 += p0 + p1;
    A[i] = pack2(p0, p1);
  }
  lsum += ts0 + ts1;
  s16x8 pf0 = __builtin_bit_cast(s16x8, (u32x4v){A[0], A[1], A[2], A[3]});
  s16x8 pf1 = __builtin_bit_cast(s16x8, (u32x4v){A[4], A[5], A[6], A[7]});
  acc = __builtin_amdgcn_mfma_f32_32x32x16_bf16(vf0, pf0, acc, 0, 0, 0);
  acc = __builtin_amdgcn_mfma_f32_32x32x16_bf16(vf1, pf1, acc, 0, 0, 0);
}

// fallback step (verified r6-r12)
template<bool MASK>
__device__ __forceinline__ void attn_stepF(const char* smem, int h, int kt,
                                           s16x8 qfh, int lane,
                                           f32x16& acc, float& lsum) {
  const int half = lane >> 5;
  const int krow = kt * 32 + (lane & 31);
  s16x8 kf = *(const s16x8*)(smem + BUF0 + krow * 256 +
                             swz(krow, h * 32 + half * 16));
  f32x16 st = __builtin_amdgcn_mfma_f32_32x32x16_bf16(kf, qfh, (f32x16){}, 0, 0, 0);
  const int vrow = h * 16 + (lane & 15);
  s16x8 vf0 = *(const s16x8*)(smem + VOFF + vrow * 512 +
                              swz(vrow, kt * 64 + half * 16));
  s16x8 vf1 = *(const s16x8*)(smem + VOFF + vrow * 512 +
                              swz(vrow, kt * 64 + 32 + half * 16));
  const int NR = MASK ? 12 : 16;
  u32 A[8];
  float ts0 = 0.f, ts1 = 0.f;
#pragma unroll
  for (int i = 0; i < 8; ++i) {
    float p0 = (2 * i < NR) ? __builtin_amdgcn_exp2f(st[2 * i]) : 0.f;
    float p1 = (2 * i + 1 < NR) ? __builtin_amdgcn_exp2f(st[2 * i + 1]) : 0.f;
    if (i & 1) ts1 += p0 + p1; else ts0 += p0 + p1;
    A[i] = pack2(p0, p1);
  }
  lsum += ts0 + ts1;
  s16x8 pf0 = __builtin_bit_cast(s16x8, (u32x4v){A[0], A[1], A[2], A[3]});
  s16x8 pf1 = __builtin_bit_cast(s16x8, (u32x4v){A[4], A[5], A[6], A[7]});
  acc = __builtin_amdgcn_mfma_f32_32x32x16_bf16(vf0, pf0, acc, 0, 0, 0);
  acc = __builtin_amdgcn_mfma_f32_32x32x16_bf16(vf1, pf1, acc, 0, 0, 0);
}

// ================= Kernel 1: LN + layout transform ==========================
// 6912 blocks = (tensor, d, h): one 24KB gload16 stage, ONE barrier, LN+write
// (compute/write code byte-identical to the r12-verified version). Block 6912
// converts W. Independent blocks overlap load/compute phases across the CU.
extern "C" __global__ __launch_bounds__(256)
void lnpre_kernel(const float* __restrict__ qm, const float* __restrict__ km,
                  const float* __restrict__ vm,
                  const float* __restrict__ gq, const float* __restrict__ bq,
                  const float* __restrict__ gkv, const float* __restrict__ bkv,
                  const float* __restrict__ pw,
                  u16* __restrict__ qn, u16* __restrict__ kn,
                  u16* __restrict__ vn, u16* __restrict__ wbf) {
  const int tid = threadIdx.x;
  const int bid = blockIdx.x;
  if (bid >= 6912) {            // W conversion: 16384 f32 -> bf16
#pragma unroll
    for (int k = 0; k < 32; ++k) {
      int idx = tid + 256 * k;
      f32x2 w2 = *(const f32x2*)(pw + idx * 2);
      ((u32*)wbf)[idx] = pack2(w2.x, w2.y);
    }
    return;
  }
  __shared__ __align__(16) float lf[6144];   // [128 ch][48 w] fp32
  __shared__ float gl[128], bl[128];
  const int t = bid / 2304, idx = bid - t * 2304;
  const float* src = t == 0 ? qm : (t == 1 ? km : vm);
  u16* dst = t == 0 ? qn : (t == 1 ? kn : vn);
  const float* gsrc = (t == 0) ? gq : gkv;
  const float* bsrc = (t == 0) ? bq : bkv;
  const float scale = (t == 0) ? QSCALE : 1.0f;
  const int d = idx / 48, h = idx - d * 48;
  const int dh = d * 2304 + h * 48;          // global token base of (d,h,0)
  const int lane = tid & 63, wv = tid >> 6;

  if (tid < 128) { gl[tid] = gsrc[tid]; bl[tid] = bsrc[tid]; }
  // stage 24KB: chunk j (16B) -> lf byte j*16 == (&lf[ch*48+wq*4]) exactly
  for (int uu = wv; uu < 24; uu += 4) {
    int j = uu * 64 + lane;
    int ch = j / 12, wq = j - ch * 12;
    gload16(src + (long)ch * SP + dh + wq * 4, (char*)lf + uu * 1024);
  }
  __syncthreads();

  if (tid < 192) {                    // thread (w, q): LN of token (d,h,w)
    const int w = tid >> 2, q = tid & 3;
    float s = 0.f, s2 = 0.f;
#pragma unroll
    for (int c = 0; c < 32; ++c) {
      float x = lf[(q + 4 * c) * 48 + w];
      s += x; s2 += x * x;
    }
    s += __shfl_xor(s, 1); s2 += __shfl_xor(s2, 1);
    s += __shfl_xor(s, 2); s2 += __shfl_xor(s2, 2);
    float m = s * (1.f / 128.f);
    float r = rsqrtf(s2 * (1.f / 128.f) - m * m + 1e-5f);
    u32x4v* op = (u32x4v*)(dst + (long)(dh + w) * 128 + 32 * q);
#pragma unroll
    for (int v4 = 0; v4 < 4; ++v4) {
      u32x4v pk;
#pragma unroll
      for (int e = 0; e < 4; ++e) {
        int ch = 32 * q + v4 * 8 + 2 * e;
        float y0 = ((lf[ch * 48 + w] - m) * r * gl[ch] + bl[ch]) * scale;
        float y1 = ((lf[(ch + 1) * 48 + w] - m) * r * gl[ch + 1] + bl[ch + 1]) * scale;
        pk[e] = pack2(y0, y1);
      }
      op[v4] = pk;
    }
  }
}

// ================= Kernel 2: attention, (window x head-half) blocks =========
// 1024 blocks x 448 threads, 61440B LDS -> 2 blocks/CU. O-half streamed
// coalesced into qn in-place (block only overwrites rows/bytes only it reads).
extern "C" __global__ __launch_bounds__(448, 4)
void attnh_kernel(u16* __restrict__ qn, const u16* __restrict__ kn,
                  const u16* __restrict__ vn) {
  __shared__ __align__(16) char smem[61440];
  const int tid = threadIdx.x, lane = tid & 63, wv = tid >> 6;
  const int half = lane >> 5;
  const int bid = blockIdx.x;
  const int wid = bid >> 1, hg = bid & 1;
  const int wd6 = (wid >> 6) * 6, wh6 = ((wid >> 3) & 7) * 6, ww6 = (wid & 7) * 6;

  // stage K-half (swz-src, 8 rows x 128B per unit)
  for (int uu = wv; uu < 27; uu += 7) {
    int row = 8 * uu + (lane >> 3);
    int tq = row / 6;
    int g = (wd6 + tq / 6) * 2304 + (wh6 + tq % 6) * 48 + ww6 + row % 6;
    gload16(kn + g * 128 + hg * 64 + (((lane & 7) ^ (row & 7)) << 3),
            smem + uu * 1024);
  }
  // stage V-half raw (linear rows [tok][64ch])
  for (int uu = wv; uu < 27; uu += 7) {
    int row = 8 * uu + (lane >> 3);
    int tq = row / 6;
    int g = (wd6 + tq / 6) * 2304 + (wh6 + tq % 6) * 48 + ww6 + row % 6;
    gload16(vn + g * 128 + hg * 64 + ((lane & 7) << 3),
            smem + VHOFF + uu * 1024);
  }
  // Q fragments direct from global (drain overlaps K/V staging)
  int qrow = wv * 32 + (lane & 31);
  if (qrow > 215) qrow = 215;
  int qtq = qrow / 6;
  int qg = (wd6 + qtq / 6) * 2304 + (wh6 + qtq % 6) * 48 + ww6 + qrow % 6;
  s16x8 qf[4];
#pragma unroll
  for (int j = 0; j < 4; ++j)
    qf[j] = *(const s16x8*)(qn + qg * 128 + (hg * 4 + j) * 16 + half * 8);
  __syncthreads();

  // V transpose: Vraw rows 0..215 -> regs -> Vt [64 ch][512B sigma(tok)]
  u32 tr[16];
#pragma unroll
  for (int k = 0; k < 8; ++k) {
    int u = tid + 448 * k;
    if (u < 3456) {
      int t = (u >> 5) * 2, c2 = u & 31;
      tr[2 * k]     = *(const u32*)(smem + VHOFF + t * 128 + c2 * 4);
      tr[2 * k + 1] = *(const u32*)(smem + VHOFF + t * 128 + 128 + c2 * 4);
    }
  }
  __syncthreads();
#pragma unroll
  for (int k = 0; k < 8; ++k) {
    int u = tid + 448 * k;
    if (u < 3456) {
      int t = (u >> 5) * 2, c2 = u & 31;
      int st = (t & ~12) | ((t & 4) << 1) | ((t & 8) >> 1);
      int c = 2 * c2;
      u32 w0 = (tr[2 * k] & 0xFFFFu) | (tr[2 * k + 1] << 16);
      u32 w1 = (tr[2 * k] >> 16) | (tr[2 * k + 1] & 0xFFFF0000u);
      *(u32*)(smem + VHOFF + c * 512 + ((st * 2) ^ ((c & 7) << 4))) = w0;
      *(u32*)(smem + VHOFF + (c + 1) * 512 + ((st * 2) ^ (((c + 1) & 7) << 4))) = w1;
    }
  }
  if (tid < 64) {   // sigma-positions {212-215,220-223} zeroed
    int x = (tid & 7) << 4;
    *(u32*)(smem + VHOFF + tid * 512 + (424 ^ x)) = 0;
    *(u32*)(smem + VHOFF + tid * 512 + (428 ^ x)) = 0;
    *(u32*)(smem + VHOFF + tid * 512 + (440 ^ x)) = 0;
    *(u32*)(smem + VHOFF + tid * 512 + (444 ^ x)) = 0;
  }
  __syncthreads();

  // attention: wave owns q rows [wv*32,+32), 4 heads (2 pairs)
  u32 oPk[4][4];
#pragma unroll
  for (int hp = 0; hp < 2; ++hp) {
    const int j0 = 2 * hp, j1 = j0 + 1;
    f32x16 a0 = {}, a1 = {};
    float l0 = 0.f, l1 = 0.f;
#pragma unroll 2
    for (int kt = 0; kt < 6; ++kt) {
      attn_stepH<false>(smem, j0, kt, qf[j0], lane, a0, l0);
      attn_stepH<false>(smem, j1, kt, qf[j1], lane, a1, l1);
    }
    attn_stepH<true>(smem, j0, 6, qf[j0], lane, a0, l0);
    attn_stepH<true>(smem, j1, 6, qf[j1], lane, a1, l1);
    l0 += __shfl_xor(l0, 32);
    l1 += __shfl_xor(l1, 32);
    float i0 = 1.0f / l0, i1 = 1.0f / l1;
#pragma unroll
    for (int r = 0; r < 4; ++r) {
      oPk[j0][r] = pack2(a0[2 * r] * i0, a0[2 * r + 1] * i0);
      oPk[j1][r] = pack2(a1[2 * r] * i1, a1[2 * r + 1] * i1);
    }
  }
  __syncthreads();   // all K reads done; reuse KH region as obuf

  // obuf: O^T regs -> [tok][128B half-row]
  {
    const int tok = wv * 32 + (lane & 31);
#pragma unroll
    for (int j = 0; j < 4; ++j) {
      int chb = j * 32 + half * 8;
      *(u32*)(smem + tok * 128 + ((chb)      ^ ((tok & 7) << 4))) = oPk[j][0];
      *(u32*)(smem + tok * 128 + ((chb + 4)  ^ ((tok & 7) << 4))) = oPk[j][1];
      *(u32*)(smem + tok * 128 + ((chb + 16) ^ ((tok & 7) << 4))) = oPk[j][2];
      *(u32*)(smem + tok * 128 + ((chb + 20) ^ ((tok & 7) << 4))) = oPk[j][3];
    }
  }
  __syncthreads();

  // stream obuf -> qn (in-place O-half; coalesced 128B pieces)
#pragma unroll
  for (int it = 0; it < 4; ++it) {
    int i = tid + 448 * it;
    int row = i >> 3;
    if (row < 216) {
      int chunk = i & 7;
      f32x4 v = *(const f32x4*)(smem + row * 128 +
                                ((chunk * 16) ^ ((row & 7) << 4)));
      int tq = row / 6;
      int g = (wd6 + tq / 6) * 2304 + (wh6 + tq % 6) * 48 + ww6 + row % 6;
      *(f32x4*)(qn + g * 128 + hg * 64 + chunk * 8) = v;
    }
  }
}

// ================= Kernel 3: projection GEMM + unwindow =====================
extern "C" __global__ __launch_bounds__(256, 3)
void proj_kernel(const u16* __restrict__ on, const u16* __restrict__ wbf,
                 const float* __restrict__ pb, float* __restrict__ out) {
  __shared__ __align__(16) char smem[45056];   // W 32768 + O 12288
  const int tid = threadIdx.x, lane = tid & 63, wv = tid >> 6;
  const int bid = blockIdx.x;
  const int dh = (bid / 48) * 2304 + (bid % 48) * 48;
  for (int uu = wv; uu < 32; uu += 4) {        // W: 128 rows x 256B
    int row = 4 * uu + (lane >> 4);
    gload16(wbf + row * 128 + (((lane & 15) ^ (row & 15)) << 3),
            smem + uu * 1024);
  }
  for (int uu = wv; uu < 12; uu += 4) {        // O: 48 rows x 256B
    int row = 4 * uu + (lane >> 4);
    gload16(on + (long)(dh + row) * 128 + (((lane & 15) ^ (row & 15)) << 3),
            smem + 32768 + uu * 1024);
  }
  __syncthreads();
#pragma unroll
  for (int jj = 0; jj < 2; ++jj) {
    int jt = wv * 2 + jj;
    int rw = jt * 16 + (lane & 15);
    s16x8 af[4];
#pragma unroll
    for (int kk = 0; kk < 4; ++kk)
      af[kk] = *(const s16x8*)(smem + rw * 256 +
                               ((kk * 64 + (lane >> 4) * 16) ^ ((rw & 15) << 4)));
    f32x4 pbv = *(const f32x4*)(pb + jt * 16 + (lane >> 4) * 4);
#pragma unroll
    for (int t = 0; t < 3; ++t) {
      int tok = t * 16 + (lane & 15);
      f32x4 acc = {};
#pragma unroll
      for (int kk = 0; kk < 4; ++kk) {
        s16x8 bfr = *(const s16x8*)(smem + 32768 + tok * 256 +
                                    ((kk * 64 + (lane >> 4) * 16) ^ ((tok & 15) << 4)));
        acc = __builtin_amdgcn_mfma_f32_16x16x32_bf16(af[kk], bfr, acc, 0, 0, 0);
      }
#pragma unroll
      for (int r = 0; r < 4; ++r) {
        int j = jt * 16 + (lane >> 4) * 4 + r;
        out[(long)j * SP + dh + tok] = acc[r] + pbv[r];
      }
    }
  }
}

// ================= Fallback: fused single kernel (r7-r12 verified) ==========
extern "C" __global__ __launch_bounds__(T1, 2)
void ca3d_kernel(const float* __restrict__ qm, const float* __restrict__ km,
                 const float* __restrict__ vm,
                 const float* __restrict__ gq, const float* __restrict__ bq,
                 const float* __restrict__ gkv, const float* __restrict__ bkv,
                 const float* __restrict__ pw, const float* __restrict__ pb,
                 float* __restrict__ out) {
  extern __shared__ __align__(16) char smem[];
  const int tid = threadIdx.x;
  const int lane = tid & 63;
  const int wv = tid >> 6;
  const int bid = blockIdx.x;
  const int wid = ((bid & 7) << 6) | (bid >> 3);
  const int wd = wid >> 6, wh = (wid >> 3) & 7, ww = wid & 7;
  const int boff = wd * 6 * 2304 + wh * 6 * 48 + ww * 6;

  for (int i = tid * 16; i < VOFF + 65536; i += T1 * 16)
    *(f32x4*)(smem + i) = (f32x4){};
  if (tid < 128) {
    ((float*)(smem + GBOFF))[tid] = gq[tid];
    ((float*)(smem + GBOFF + 512))[tid] = bq[tid];
    ((float*)(smem + GBOFF + 1024))[tid] = gkv[tid];
    ((float*)(smem + GBOFF + 1536))[tid] = bkv[tid];
  }
  const bool lnAct = tid < 432;
  const int tp = tid >> 2;
  const int cbase = (tid & 3) * 32;
  const int tA = tp * 2, tB = tA + 1;
  int td = tA / 36, tr_ = tA - td * 36;
  int th_ = tr_ / 6, tw_ = tr_ - th_ * 6;
  const int gpos = boff + td * 2304 + th_ * 48 + tw_;
  const int vposA = (tA & ~0xC) | ((tA & 4) << 1) | ((tA & 8) >> 1);

  f32x2 qv[32], kv[32], vv[32];
  if (lnAct) {
#pragma unroll
    for (int c = 0; c < 32; ++c)
      qv[c] = *(const f32x2*)(qm + gpos + (cbase + c) * SP);
#pragma unroll
    for (int c = 0; c < 32; ++c)
      kv[c] = *(const f32x2*)(km + gpos + (cbase + c) * SP);
  }
  __syncthreads();
  const float* gql = (const float*)(smem + GBOFF);
  const float* bql = (const float*)(smem + GBOFF + 512);
  const float* gkl = (const float*)(smem + GBOFF + 1024);
  const float* bkl = (const float*)(smem + GBOFF + 1536);
  if (lnAct) {
    float mA, rA, mB, rB;
    ln_stats(qv, mA, rA, mB, rB);
#pragma unroll
    for (int c = 0; c < 32; c += 2) {
      int cc = cbase + c;
      float g0 = gql[cc], g1 = gql[cc + 1], b0 = bql[cc], b1 = bql[cc + 1];
      *(u32*)(smem + BUF0 + tA * 256 + swz(tA, cc * 2)) =
          pack2(((qv[c].x - mA) * rA * g0 + b0) * QSCALE,
                ((qv[c + 1].x - mA) * rA * g1 + b1) * QSCALE);
      *(u32*)(smem + BUF0 + tB * 256 + swz(tB, cc * 2)) =
          pack2(((qv[c].y - mB) * rB * g0 + b0) * QSCALE,
                ((qv[c + 1].y - mB) * rB * g1 + b1) * QSCALE);
    }
#pragma unroll
    for (int c = 0; c < 32; ++c)
      vv[c] = *(const f32x2*)(vm + gpos + (cbase + c) * SP);
  }
  __syncthreads();
  s16x8 qf[8];
  {
    int row = wv * 32 + (lane & 31);
    int ib = (lane >> 5) * 16;
#pragma unroll
    for (int h = 0; h < 8; ++h)
      qf[h] = *(const s16x8*)(smem + BUF0 + row * 256 + swz(row, h * 32 + ib));
  }
  __syncthreads();
  if (lnAct) {
    {
      float mA, rA, mB, rB;
      ln_stats(kv, mA, rA, mB, rB);
#pragma unroll
      for (int c = 0; c < 32; c += 2) {
        int cc = cbase + c;
        float g0 = gkl[cc], g1 = gkl[cc + 1], b0 = bkl[cc], b1 = bkl[cc + 1];
        *(u32*)(smem + BUF0 + tA * 256 + swz(tA, cc * 2)) =
            pack2((kv[c].x - mA) * rA * g0 + b0,
                  (kv[c + 1].x - mA) * rA * g1 + b1);
        *(u32*)(smem + BUF0 + tB * 256 + swz(tB, cc * 2)) =
            pack2((kv[c].y - mB) * rB * g0 + b0,
                  (kv[c + 1].y - mB) * rB * g1 + b1);
      }
    }
    {
      float mA, rA, mB, rB;
      ln_stats(vv, mA, rA, mB, rB);
#pragma unroll
      for (int c = 0; c < 32; ++c) {
        int cc = cbase + c;
        float g0 = gkl[cc], b0 = bkl[cc];
        *(u32*)(smem + VOFF + cc * 512 + swz(cc, vposA * 2)) =
            pack2((vv[c].x - mA) * rA * g0 + b0,
                  (vv[c].y - mB) * rB * g0 + b0);
      }
    }
  }
  for (int i = tid; i < 8192; i += T1) {
    int j = i >> 6, c2 = i & 63;
    f32x2 w2 = *(const f32x2*)(pw + j * 128 + c2 * 2);
    *(u32*)(smem + WOFF + j * 256 + swz(j, c2 * 4)) = pack2(w2.x, w2.y);
  }
  __syncthreads();
  u32 oPk[8][4];
#pragma unroll
  for (int hp = 0; hp < 4; ++hp) {
    const int h0 = hp * 2, h1 = h0 + 1;
    f32x16 a0 = {}, a1 = {};
    float l0 = 0.f, l1 = 0.f;
#pragma unroll 1
    for (int kt = 0; kt < 6; ++kt) {
      attn_stepF<false>(smem, h0, kt, qf[h0], lane, a0, l0);
      attn_stepF<false>(smem, h1, kt, qf[h1], lane, a1, l1);
    }
    attn_stepF<true>(smem, h0, 6, qf[h0], lane, a0, l0);
    attn_stepF<true>(smem, h1, 6, qf[h1], lane, a1, l1);
    l0 += __shfl_xor(l0, 32);
    l1 += __shfl_xor(l1, 32);
    float i0 = 1.0f / l0, i1 = 1.0f / l1;
#pragma unroll
    for (int r = 0; r < 4; ++r) {
      oPk[h0][r] = pack2(a0[2 * r] * i0, a0[2 * r + 1] * i0);
      oPk[h1][r] = pack2(a1[2 * r] * i1, a1[2 * r + 1] * i1);
    }
  }
  __syncthreads();
  {
    const int tok = wv * 32 + (lane & 31);
    const int half = lane >> 5;
#pragma unroll
    for (int h = 0; h < 8; ++h) {
      int chb = h * 32 + half * 8;
      *(u32*)(smem + BUF0 + tok * 256 + swz(tok, chb))      = oPk[h][0];
      *(u32*)(smem + BUF0 + tok * 256 + swz(tok, chb + 4))  = oPk[h][1];
      *(u32*)(smem + BUF0 + tok * 256 + swz(tok, chb + 16)) = oPk[h][2];
      *(u32*)(smem + BUF0 + tok * 256 + swz(tok, chb + 20)) = oPk[h][3];
    }
  }
  __syncthreads();
#pragma unroll 1
  for (int ti = 0; ti < 2; ++ti) {
    int tt = wv * 2 + ti;
    int tok = tt * 16 + (lane & 15);
    s16x8 bfr[4];
#pragma unroll
    for (int kk = 0; kk < 4; ++kk)
      bfr[kk] = *(const s16x8*)(smem + BUF0 + tok * 256 +
                                swz(tok, kk * 64 + (lane >> 4) * 16));
    bool tokValid = tok < TOK;
    int tdd = tok / 36, trr = tok - tdd * 36;
    int thh = trr / 6, tww = trr - thh * 6;
    int pos = boff + tdd * 2304 + thh * 48 + tww;
#pragma unroll 1
    for (int jt = 0; jt < 8; ++jt) {
      f32x4 acc = {};
#pragma unroll
      for (int kk = 0; kk < 4; ++kk) {
        int rw = jt * 16 + (lane & 15);
        s16x8 af = *(const s16x8*)(smem + WOFF + rw * 256 +
                                   swz(rw, kk * 64 + (lane >> 4) * 16));
        acc = __builtin_amdgcn_mfma_f32_16x16x32_bf16(af, bfr[kk], acc, 0, 0, 0);
      }
      f32x4 pbv = *(const f32x4*)(pb + jt * 16 + (lane >> 4) * 4);
      if (tokValid) {
#pragma unroll
        for (int r = 0; r < 4; ++r) {
          int j = jt * 16 + (lane >> 4) * 4 + r;
          out[j * SP + pos] = acc[r] + pbv[r];
        }
      }
    }
  }
}

extern "C" void kernel_launch(void* const* d_in, const int* in_sizes, int n_in,
                              void* d_out, int out_size, void* d_ws, size_t ws_size,
                              hipStream_t stream) {
  const float* qm  = (const float*)d_in[0];
  const float* km  = (const float*)d_in[1];
  const float* vm  = (const float*)d_in[2];
  const float* gq  = (const float*)d_in[3];
  const float* bq  = (const float*)d_in[4];
  const float* gkv = (const float*)d_in[5];
  const float* bkv = (const float*)d_in[6];
  const float* pw  = (const float*)d_in[7];
  const float* pb  = (const float*)d_in[8];
  if (ws_size >= WSNEED) {
    u16* qn  = (u16*)d_ws;                       // Q, then O in-place
    u16* kn  = (u16*)((char*)d_ws + TENB);
    u16* vn  = (u16*)((char*)d_ws + 2 * TENB);
    u16* wbf = (u16*)((char*)d_ws + 3 * TENB);
    hipLaunchKernelGGL(lnpre_kernel, dim3(6913), dim3(256), 0, stream,
                       qm, km, vm, gq, bq, gkv, bkv, pw, qn, kn, vn, wbf);
    hipLaunchKernelGGL(attnh_kernel, dim3(1024), dim3(448), 0, stream,
                       qn, kn, vn);
    hipLaunchKernelGGL(proj_kernel, dim3(2304), dim3(256), 0, stream,
                       qn, wbf, pb, (float*)d_out);
  } else {
    hipLaunchKernelGGL(ca3d_kernel, dim3(512), dim3(T1), LDS_OLD, stream,
                       qm, km, vm, gq, bq, gkv, bkv, pw, pb, (float*)d_out);
  }
}

// Round 14
// 136.105 us; speedup vs baseline: 1.7032x; 1.0063x over previous
//
#include <hip/hip_runtime.h>
#include <hip/hip_bf16.h>

typedef short s16x8 __attribute__((ext_vector_type(8)));
typedef float f32x2 __attribute__((ext_vector_type(2)));
typedef float f32x4 __attribute__((ext_vector_type(4)));
typedef float f32x16 __attribute__((ext_vector_type(16)));
typedef unsigned int u32;
typedef unsigned short u16;
typedef u32 u32x4v __attribute__((ext_vector_type(4)));

#define TOK 216
#define T1 448
#define SP 110592
// fallback LDS map
#define BUF0 0
#define VOFF 57344
#define WOFF 122880
#define GBOFF 155648
#define LDS_OLD 157696
// attnh LDS map: KH [224 rows x 128B] then obuf; VHOFF Vraw(27KB)->Vt 64x512B
#define VHOFF 28672
#define TENB 28311552ull
#define WSNEED (3ull*TENB + 32768ull)
#define QSCALE 0.360673760f // 0.25 * log2(e): scores*log2e -> exp2

__device__ __forceinline__ u32 pack2(float a, float b) {
  u16 lo = __builtin_bit_cast(u16, __float2bfloat16(a));
  u16 hi = __builtin_bit_cast(u16, __float2bfloat16(b));
  return (u32)lo | ((u32)hi << 16);
}
__device__ __forceinline__ int swz(int row, int inner) {
  return inner ^ ((row & 7) << 4);
}
__device__ __forceinline__ void gload16(const void* g, void* l) {
  __builtin_amdgcn_global_load_lds(
      (const __attribute__((address_space(1))) void*)g,
      (__attribute__((address_space(3))) void*)l, 16, 0, 0);
}

__device__ __forceinline__ void ln_stats(const f32x2* xv, float& mA, float& rA,
                                         float& mB, float& rB) {
  float sA = 0.f, s2A = 0.f, sB = 0.f, s2B = 0.f;
#pragma unroll
  for (int c = 0; c < 32; ++c) {
    sA += xv[c].x; s2A += xv[c].x * xv[c].x;
    sB += xv[c].y; s2B += xv[c].y * xv[c].y;
  }
  sA += __shfl_xor(sA, 1); s2A += __shfl_xor(s2A, 1);
  sB += __shfl_xor(sB, 1); s2B += __shfl_xor(s2B, 1);
  sA += __shfl_xor(sA, 2); s2A += __shfl_xor(s2A, 2);
  sB += __shfl_xor(sB, 2); s2B += __shfl_xor(s2B, 2);
  mA = sA * (1.0f / 128.0f);
  rA = rsqrtf(s2A * (1.0f / 128.0f) - mA * mA + 1e-5f);
  mB = sB * (1.0f / 128.0f);
  rB = rsqrtf(s2B * (1.0f / 128.0f) - mB * mB + 1e-5f);
}

// attnh step: head-half tiles (K rows 128B, V-half 64 ch-rows). Verified
// r6-r13 math with half-width indexing. No-max softmax (exp2, log2e in Q);
// sigma-permuted V so packed P regs ARE the PV B-fragments.
template<bool MASK>
__device__ __forceinline__ void attn_stepH(const char* smem, int jloc, int kt,
                                           s16x8 qfh, int lane,
                                           f32x16& acc, float& lsum) {
  const int half = lane >> 5;
  const int krow = kt * 32 + (lane & 31);
  s16x8 kf = *(const s16x8*)(smem + krow * 128 +
                             ((jloc * 32 + half * 16) ^ ((krow & 7) << 4)));
  f32x16 st = __builtin_amdgcn_mfma_f32_32x32x16_bf16(kf, qfh, (f32x16){}, 0, 0, 0);
  const int vrow = jloc * 16 + (lane & 15);
  s16x8 vf0 = *(const s16x8*)(smem + VHOFF + vrow * 512 +
                              ((kt * 64 + half * 16) ^ ((vrow & 7) << 4)));
  s16x8 vf1 = *(const s16x8*)(smem + VHOFF + vrow * 512 +
                              ((kt * 64 + 32 + half * 16) ^ ((vrow & 7) << 4)));
  const int NR = MASK ? 12 : 16;
  u32 A[8];
  float ts0 = 0.f, ts1 = 0.f;
#pragma unroll
  for (int i = 0; i < 8; ++i) {
    float p0 = (2 * i < NR) ? __builtin_amdgcn_exp2f(st[2 * i]) : 0.f;
    float p1 = (2 * i + 1 < NR) ? __builtin_amdgcn_exp2f(st[2 * i + 1]) : 0.f;
    if (i & 1) ts1 += p0 + p1; else ts0 += p0 + p1;
    A[i] = pack2(p0, p1);
  }
  lsum += ts0 + ts1;
  s16x8 pf0 = __builtin_bit_cast(s16x8, (u32x4v){A[0], A[1], A[2], A[3]});
  s16x8 pf1 = __builtin_bit_cast(s16x8, (u32x4v){A[4], A[5], A[6], A[7]});
  acc = __builtin_amdgcn_mfma_f32_32x32x16_bf16(vf0, pf0, acc, 0, 0, 0);
  acc = __builtin_amdgcn_mfma_f32_32x32x16_bf16(vf1, pf1, acc, 0, 0, 0);
}

// fallback step (verified r6-r13)
template<bool MASK>
__device__ __forceinline__ void attn_stepF(const char* smem, int h, int kt,
                                           s16x8 qfh, int lane,
                                           f32x16& acc, float& lsum) {
  const int half = lane >> 5;
  const int krow = kt * 32 + (lane & 31);
  s16x8 kf = *(const s16x8*)(smem + BUF0 + krow * 256 +
                             swz(krow, h * 32 + half * 16));
  f32x16 st = __builtin_amdgcn_mfma_f32_32x32x16_bf16(kf, qfh, (f32x16){}, 0, 0, 0);
  const int vrow = h * 16 + (lane & 15);
  s16x8 vf0 = *(const s16x8*)(smem + VOFF + vrow * 512 +
                              swz(vrow, kt * 64 + half * 16));
  s16x8 vf1 = *(const s16x8*)(smem + VOFF + vrow * 512 +
                              swz(vrow, kt * 64 + 32 + half * 16));
  const int NR = MASK ? 12 : 16;
  u32 A[8];
  float ts0 = 0.f, ts1 = 0.f;
#pragma unroll
  for (int i = 0; i < 8; ++i) {
    float p0 = (2 * i < NR) ? __builtin_amdgcn_exp2f(st[2 * i]) : 0.f;
    float p1 = (2 * i + 1 < NR) ? __builtin_amdgcn_exp2f(st[2 * i + 1]) : 0.f;
    if (i & 1) ts1 += p0 + p1; else ts0 += p0 + p1;
    A[i] = pack2(p0, p1);
  }
  lsum += ts0 + ts1;
  s16x8 pf0 = __builtin_bit_cast(s16x8, (u32x4v){A[0], A[1], A[2], A[3]});
  s16x8 pf1 = __builtin_bit_cast(s16x8, (u32x4v){A[4], A[5], A[6], A[7]});
  acc = __builtin_amdgcn_mfma_f32_32x32x16_bf16(vf0, pf0, acc, 0, 0, 0);
  acc = __builtin_amdgcn_mfma_f32_32x32x16_bf16(vf1, pf1, acc, 0, 0, 0);
}

// ================= Kernel 1: LN over contiguous 144-token spans =============
// 2304 blocks = (tensor, span of 144 consecutive tokens = 3 h-lines).
// Reads [128 ch][144 tok] fp32 as 128 runs of 576B (3x the (d,h)-block run
// length -> fewer DRAM row activations); writes 36KB fully contiguous bf16.
// LDS 74.8KB -> 2 blocks/CU so staging/compute phases overlap across blocks.
// LN compute is the r12/r13-verified code with stride 48->144 (stats reads
// now 2-way bank-free: 144 % 32 == 16). Block 2304 converts W.
extern "C" __global__ __launch_bounds__(256)
void lnpre_kernel(const float* __restrict__ qm, const float* __restrict__ km,
                  const float* __restrict__ vm,
                  const float* __restrict__ gq, const float* __restrict__ bq,
                  const float* __restrict__ gkv, const float* __restrict__ bkv,
                  const float* __restrict__ pw,
                  u16* __restrict__ qn, u16* __restrict__ kn,
                  u16* __restrict__ vn, u16* __restrict__ wbf) {
  const int tid = threadIdx.x;
  const int bid = blockIdx.x;
  if (bid >= 2304) {            // W conversion: 16384 f32 -> bf16
#pragma unroll
    for (int k = 0; k < 32; ++k) {
      int idx = tid + 256 * k;
      f32x2 w2 = *(const f32x2*)(pw + idx * 2);
      ((u32*)wbf)[idx] = pack2(w2.x, w2.y);
    }
    return;
  }
  __shared__ __align__(16) float lf[18432];   // [128 ch][144 tok] fp32
  __shared__ float gl[128], bl[128];
  const int t = bid / 768, span = bid - t * 768;
  const float* src = t == 0 ? qm : (t == 1 ? km : vm);
  u16* dst = t == 0 ? qn : (t == 1 ? kn : vn);
  const float* gsrc = (t == 0) ? gq : gkv;
  const float* bsrc = (t == 0) ? bq : bkv;
  const float scale = (t == 0) ? QSCALE : 1.0f;
  const int T0 = span * 144;                  // global token base
  const int lane = tid & 63, wv = tid >> 6;

  if (tid < 128) { gl[tid] = gsrc[tid]; bl[tid] = bsrc[tid]; }
  // stage 72KB: unit j (16B) -> lf byte j*16 ; j = ch*36 + u, src run 576B/ch
  for (int uu = wv; uu < 72; uu += 4) {
    int j = uu * 64 + lane;
    int ch = j / 36, u = j - ch * 36;
    gload16(src + (long)ch * SP + T0 + u * 4, (char*)lf + uu * 1024);
  }
  __syncthreads();

  // LN: task = (token i in span, ch-quadrant q); 576 tasks over 3 rounds
#pragma unroll 1
  for (int z = 0; z < 3; ++z) {
    int task = z * 256 + tid;
    if (task < 576) {
      const int i = task >> 2, q = task & 3;
      float s = 0.f, s2 = 0.f;
#pragma unroll
      for (int c = 0; c < 32; ++c) {
        float x = lf[(q + 4 * c) * 144 + i];
        s += x; s2 += x * x;
      }
      s += __shfl_xor(s, 1); s2 += __shfl_xor(s2, 1);
      s += __shfl_xor(s, 2); s2 += __shfl_xor(s2, 2);
      float m = s * (1.f / 128.f);
      float r = rsqrtf(s2 * (1.f / 128.f) - m * m + 1e-5f);
      u32x4v* op = (u32x4v*)(dst + (long)(T0 + i) * 128 + 32 * q);
#pragma unroll
      for (int v4 = 0; v4 < 4; ++v4) {
        u32x4v pk;
#pragma unroll
        for (int e = 0; e < 4; ++e) {
          int ch = 32 * q + v4 * 8 + 2 * e;
          float y0 = ((lf[ch * 144 + i] - m) * r * gl[ch] + bl[ch]) * scale;
          float y1 = ((lf[(ch + 1) * 144 + i] - m) * r * gl[ch + 1] + bl[ch + 1]) * scale;
          pk[e] = pack2(y0, y1);
        }
        op[v4] = pk;
      }
    }
  }
}

// ================= Kernel 2: attention, (window x head-half) blocks =========
// 1024 blocks x 448 threads, 61440B LDS -> 2 blocks/CU. O-half streamed
// coalesced into qn in-place (block only overwrites rows/bytes only it reads).
extern "C" __global__ __launch_bounds__(448, 4)
void attnh_kernel(u16* __restrict__ qn, const u16* __restrict__ kn,
                  const u16* __restrict__ vn) {
  __shared__ __align__(16) char smem[61440];
  const int tid = threadIdx.x, lane = tid & 63, wv = tid >> 6;
  const int half = lane >> 5;
  const int bid = blockIdx.x;
  const int wid = bid >> 1, hg = bid & 1;
  const int wd6 = (wid >> 6) * 6, wh6 = ((wid >> 3) & 7) * 6, ww6 = (wid & 7) * 6;

  // stage K-half (swz-src, 8 rows x 128B per unit)
  for (int uu = wv; uu < 27; uu += 7) {
    int row = 8 * uu + (lane >> 3);
    int tq = row / 6;
    int g = (wd6 + tq / 6) * 2304 + (wh6 + tq % 6) * 48 + ww6 + row % 6;
    gload16(kn + g * 128 + hg * 64 + (((lane & 7) ^ (row & 7)) << 3),
            smem + uu * 1024);
  }
  // stage V-half raw (linear rows [tok][64ch])
  for (int uu = wv; uu < 27; uu += 7) {
    int row = 8 * uu + (lane >> 3);
    int tq = row / 6;
    int g = (wd6 + tq / 6) * 2304 + (wh6 + tq % 6) * 48 + ww6 + row % 6;
    gload16(vn + g * 128 + hg * 64 + ((lane & 7) << 3),
            smem + VHOFF + uu * 1024);
  }
  // Q fragments direct from global (drain overlaps K/V staging)
  int qrow = wv * 32 + (lane & 31);
  if (qrow > 215) qrow = 215;
  int qtq = qrow / 6;
  int qg = (wd6 + qtq / 6) * 2304 + (wh6 + qtq % 6) * 48 + ww6 + qrow % 6;
  s16x8 qf[4];
#pragma unroll
  for (int j = 0; j < 4; ++j)
    qf[j] = *(const s16x8*)(qn + qg * 128 + (hg * 4 + j) * 16 + half * 8);
  __syncthreads();

  // V transpose: Vraw rows 0..215 -> regs -> Vt [64 ch][512B sigma(tok)]
  u32 tr[16];
#pragma unroll
  for (int k = 0; k < 8; ++k) {
    int u = tid + 448 * k;
    if (u < 3456) {
      int t = (u >> 5) * 2, c2 = u & 31;
      tr[2 * k]     = *(const u32*)(smem + VHOFF + t * 128 + c2 * 4);
      tr[2 * k + 1] = *(const u32*)(smem + VHOFF + t * 128 + 128 + c2 * 4);
    }
  }
  __syncthreads();
#pragma unroll
  for (int k = 0; k < 8; ++k) {
    int u = tid + 448 * k;
    if (u < 3456) {
      int t = (u >> 5) * 2, c2 = u & 31;
      int st = (t & ~12) | ((t & 4) << 1) | ((t & 8) >> 1);
      int c = 2 * c2;
      u32 w0 = (tr[2 * k] & 0xFFFFu) | (tr[2 * k + 1] << 16);
      u32 w1 = (tr[2 * k] >> 16) | (tr[2 * k + 1] & 0xFFFF0000u);
      *(u32*)(smem + VHOFF + c * 512 + ((st * 2) ^ ((c & 7) << 4))) = w0;
      *(u32*)(smem + VHOFF + (c + 1) * 512 + ((st * 2) ^ (((c + 1) & 7) << 4))) = w1;
    }
  }
  if (tid < 64) {   // sigma-positions {212-215,220-223} zeroed
    int x = (tid & 7) << 4;
    *(u32*)(smem + VHOFF + tid * 512 + (424 ^ x)) = 0;
    *(u32*)(smem + VHOFF + tid * 512 + (428 ^ x)) = 0;
    *(u32*)(smem + VHOFF + tid * 512 + (440 ^ x)) = 0;
    *(u32*)(smem + VHOFF + tid * 512 + (444 ^ x)) = 0;
  }
  __syncthreads();

  // attention: wave owns q rows [wv*32,+32), 4 heads (2 pairs)
  u32 oPk[4][4];
#pragma unroll
  for (int hp = 0; hp < 2; ++hp) {
    const int j0 = 2 * hp, j1 = j0 + 1;
    f32x16 a0 = {}, a1 = {};
    float l0 = 0.f, l1 = 0.f;
#pragma unroll 2
    for (int kt = 0; kt < 6; ++kt) {
      attn_stepH<false>(smem, j0, kt, qf[j0], lane, a0, l0);
      attn_stepH<false>(smem, j1, kt, qf[j1], lane, a1, l1);
    }
    attn_stepH<true>(smem, j0, 6, qf[j0], lane, a0, l0);
    attn_stepH<true>(smem, j1, 6, qf[j1], lane, a1, l1);
    l0 += __shfl_xor(l0, 32);
    l1 += __shfl_xor(l1, 32);
    float i0 = 1.0f / l0, i1 = 1.0f / l1;
#pragma unroll
    for (int r = 0; r < 4; ++r) {
      oPk[j0][r] = pack2(a0[2 * r] * i0, a0[2 * r + 1] * i0);
      oPk[j1][r] = pack2(a1[2 * r] * i1, a1[2 * r + 1] * i1);
    }
  }
  __syncthreads();   // all K reads done; reuse KH region as obuf

  // obuf: O^T regs -> [tok][128B half-row]
  {
    const int tok = wv * 32 + (lane & 31);
#pragma unroll
    for (int j = 0; j < 4; ++j) {
      int chb = j * 32 + half * 8;
      *(u32*)(smem + tok * 128 + ((chb)      ^ ((tok & 7) << 4))) = oPk[j][0];
      *(u32*)(smem + tok * 128 + ((chb + 4)  ^ ((tok & 7) << 4))) = oPk[j][1];
      *(u32*)(smem + tok * 128 + ((chb + 16) ^ ((tok & 7) << 4))) = oPk[j][2];
      *(u32*)(smem + tok * 128 + ((chb + 20) ^ ((tok & 7) << 4))) = oPk[j][3];
    }
  }
  __syncthreads();

  // stream obuf -> qn (in-place O-half; coalesced 128B pieces)
#pragma unroll
  for (int it = 0; it < 4; ++it) {
    int i = tid + 448 * it;
    int row = i >> 3;
    if (row < 216) {
      int chunk = i & 7;
      f32x4 v = *(const f32x4*)(smem + row * 128 +
                                ((chunk * 16) ^ ((row & 7) << 4)));
      int tq = row / 6;
      int g = (wd6 + tq / 6) * 2304 + (wh6 + tq % 6) * 48 + ww6 + row % 6;
      *(f32x4*)(qn + g * 128 + hg * 64 + chunk * 8) = v;
    }
  }
}

// ================= Kernel 3: projection GEMM + unwindow =====================
extern "C" __global__ __launch_bounds__(256, 3)
void proj_kernel(const u16* __restrict__ on, const u16* __restrict__ wbf,
                 const float* __restrict__ pb, float* __restrict__ out) {
  __shared__ __align__(16) char smem[45056];   // W 32768 + O 12288
  const int tid = threadIdx.x, lane = tid & 63, wv = tid >> 6;
  const int bid = blockIdx.x;
  const int dh = (bid / 48) * 2304 + (bid % 48) * 48;
  for (int uu = wv; uu < 32; uu += 4) {        // W: 128 rows x 256B
    int row = 4 * uu + (lane >> 4);
    gload16(wbf + row * 128 + (((lane & 15) ^ (row & 15)) << 3),
            smem + uu * 1024);
  }
  for (int uu = wv; uu < 12; uu += 4) {        // O: 48 rows x 256B
    int row = 4 * uu + (lane >> 4);
    gload16(on + (long)(dh + row) * 128 + (((lane & 15) ^ (row & 15)) << 3),
            smem + 32768 + uu * 1024);
  }
  __syncthreads();
#pragma unroll
  for (int jj = 0; jj < 2; ++jj) {
    int jt = wv * 2 + jj;
    int rw = jt * 16 + (lane & 15);
    s16x8 af[4];
#pragma unroll
    for (int kk = 0; kk < 4; ++kk)
      af[kk] = *(const s16x8*)(smem + rw * 256 +
                               ((kk * 64 + (lane >> 4) * 16) ^ ((rw & 15) << 4)));
    f32x4 pbv = *(const f32x4*)(pb + jt * 16 + (lane >> 4) * 4);
#pragma unroll
    for (int t = 0; t < 3; ++t) {
      int tok = t * 16 + (lane & 15);
      f32x4 acc = {};
#pragma unroll
      for (int kk = 0; kk < 4; ++kk) {
        s16x8 bfr = *(const s16x8*)(smem + 32768 + tok * 256 +
                                    ((kk * 64 + (lane >> 4) * 16) ^ ((tok & 15) << 4)));
        acc = __builtin_amdgcn_mfma_f32_16x16x32_bf16(af[kk], bfr, acc, 0, 0, 0);
      }
#pragma unroll
      for (int r = 0; r < 4; ++r) {
        int j = jt * 16 + (lane >> 4) * 4 + r;
        out[(long)j * SP + dh + tok] = acc[r] + pbv[r];
      }
    }
  }
}

// ================= Fallback: fused single kernel (r7-r13 verified) ==========
extern "C" __global__ __launch_bounds__(T1, 2)
void ca3d_kernel(const float* __restrict__ qm, const float* __restrict__ km,
                 const float* __restrict__ vm,
                 const float* __restrict__ gq, const float* __restrict__ bq,
                 const float* __restrict__ gkv, const float* __restrict__ bkv,
                 const float* __restrict__ pw, const float* __restrict__ pb,
                 float* __restrict__ out) {
  extern __shared__ __align__(16) char smem[];
  const int tid = threadIdx.x;
  const int lane = tid & 63;
  const int wv = tid >> 6;
  const int bid = blockIdx.x;
  const int wid = ((bid & 7) << 6) | (bid >> 3);
  const int wd = wid >> 6, wh = (wid >> 3) & 7, ww = wid & 7;
  const int boff = wd * 6 * 2304 + wh * 6 * 48 + ww * 6;

  for (int i = tid * 16; i < VOFF + 65536; i += T1 * 16)
    *(f32x4*)(smem + i) = (f32x4){};
  if (tid < 128) {
    ((float*)(smem + GBOFF))[tid] = gq[tid];
    ((float*)(smem + GBOFF + 512))[tid] = bq[tid];
    ((float*)(smem + GBOFF + 1024))[tid] = gkv[tid];
    ((float*)(smem + GBOFF + 1536))[tid] = bkv[tid];
  }
  const bool lnAct = tid < 432;
  const int tp = tid >> 2;
  const int cbase = (tid & 3) * 32;
  const int tA = tp * 2, tB = tA + 1;
  int td = tA / 36, tr_ = tA - td * 36;
  int th_ = tr_ / 6, tw_ = tr_ - th_ * 6;
  const int gpos = boff + td * 2304 + th_ * 48 + tw_;
  const int vposA = (tA & ~0xC) | ((tA & 4) << 1) | ((tA & 8) >> 1);

  f32x2 qv[32], kv[32], vv[32];
  if (lnAct) {
#pragma unroll
    for (int c = 0; c < 32; ++c)
      qv[c] = *(const f32x2*)(qm + gpos + (cbase + c) * SP);
#pragma unroll
    for (int c = 0; c < 32; ++c)
      kv[c] = *(const f32x2*)(km + gpos + (cbase + c) * SP);
  }
  __syncthreads();
  const float* gql = (const float*)(smem + GBOFF);
  const float* bql = (const float*)(smem + GBOFF + 512);
  const float* gkl = (const float*)(smem + GBOFF + 1024);
  const float* bkl = (const float*)(smem + GBOFF + 1536);
  if (lnAct) {
    float mA, rA, mB, rB;
    ln_stats(qv, mA, rA, mB, rB);
#pragma unroll
    for (int c = 0; c < 32; c += 2) {
      int cc = cbase + c;
      float g0 = gql[cc], g1 = gql[cc + 1], b0 = bql[cc], b1 = bql[cc + 1];
      *(u32*)(smem + BUF0 + tA * 256 + swz(tA, cc * 2)) =
          pack2(((qv[c].x - mA) * rA * g0 + b0) * QSCALE,
                ((qv[c + 1].x - mA) * rA * g1 + b1) * QSCALE);
      *(u32*)(smem + BUF0 + tB * 256 + swz(tB, cc * 2)) =
          pack2(((qv[c].y - mB) * rB * g0 + b0) * QSCALE,
                ((qv[c + 1].y - mB) * rB * g1 + b1) * QSCALE);
    }
#pragma unroll
    for (int c = 0; c < 32; ++c)
      vv[c] = *(const f32x2*)(vm + gpos + (cbase + c) * SP);
  }
  __syncthreads();
  s16x8 qf[8];
  {
    int row = wv * 32 + (lane & 31);
    int ib = (lane >> 5) * 16;
#pragma unroll
    for (int h = 0; h < 8; ++h)
      qf[h] = *(const s16x8*)(smem + BUF0 + row * 256 + swz(row, h * 32 + ib));
  }
  __syncthreads();
  if (lnAct) {
    {
      float mA, rA, mB, rB;
      ln_stats(kv, mA, rA, mB, rB);
#pragma unroll
      for (int c = 0; c < 32; c += 2) {
        int cc = cbase + c;
        float g0 = gkl[cc], g1 = gkl[cc + 1], b0 = bkl[cc], b1 = bkl[cc + 1];
        *(u32*)(smem + BUF0 + tA * 256 + swz(tA, cc * 2)) =
            pack2((kv[c].x - mA) * rA * g0 + b0,
                  (kv[c + 1].x - mA) * rA * g1 + b1);
        *(u32*)(smem + BUF0 + tB * 256 + swz(tB, cc * 2)) =
            pack2((kv[c].y - mB) * rB * g0 + b0,
                  (kv[c + 1].y - mB) * rB * g1 + b1);
      }
    }
    {
      float mA, rA, mB, rB;
      ln_stats(vv, mA, rA, mB, rB);
#pragma unroll
      for (int c = 0; c < 32; ++c) {
        int cc = cbase + c;
        float g0 = gkl[cc], b0 = bkl[cc];
        *(u32*)(smem + VOFF + cc * 512 + swz(cc, vposA * 2)) =
            pack2((vv[c].x - mA) * rA * g0 + b0,
                  (vv[c].y - mB) * rB * g0 + b0);
      }
    }
  }
  for (int i = tid; i < 8192; i += T1) {
    int j = i >> 6, c2 = i & 63;
    f32x2 w2 = *(const f32x2*)(pw + j * 128 + c2 * 2);
    *(u32*)(smem + WOFF + j * 256 + swz(j, c2 * 4)) = pack2(w2.x, w2.y);
  }
  __syncthreads();
  u32 oPk[8][4];
#pragma unroll
  for (int hp = 0; hp < 4; ++hp) {
    const int h0 = hp * 2, h1 = h0 + 1;
    f32x16 a0 = {}, a1 = {};
    float l0 = 0.f, l1 = 0.f;
#pragma unroll 1
    for (int kt = 0; kt < 6; ++kt) {
      attn_stepF<false>(smem, h0, kt, qf[h0], lane, a0, l0);
      attn_stepF<false>(smem, h1, kt, qf[h1], lane, a1, l1);
    }
    attn_stepF<true>(smem, h0, 6, qf[h0], lane, a0, l0);
    attn_stepF<true>(smem, h1, 6, qf[h1], lane, a1, l1);
    l0 += __shfl_xor(l0, 32);
    l1 += __shfl_xor(l1, 32);
    float i0 = 1.0f / l0, i1 = 1.0f / l1;
#pragma unroll
    for (int r = 0; r < 4; ++r) {
      oPk[h0][r] = pack2(a0[2 * r] * i0, a0[2 * r + 1] * i0);
      oPk[h1][r] = pack2(a1[2 * r] * i1, a1[2 * r + 1] * i1);
    }
  }
  __syncthreads();
  {
    const int tok = wv * 32 + (lane & 31);
    const int half = lane >> 5;
#pragma unroll
    for (int h = 0; h < 8; ++h) {
      int chb = h * 32 + half * 8;
      *(u32*)(smem + BUF0 + tok * 256 + swz(tok, chb))      = oPk[h][0];
      *(u32*)(smem + BUF0 + tok * 256 + swz(tok, chb + 4))  = oPk[h][1];
      *(u32*)(smem + BUF0 + tok * 256 + swz(tok, chb + 16)) = oPk[h][2];
      *(u32*)(smem + BUF0 + tok * 256 + swz(tok, chb + 20)) = oPk[h][3];
    }
  }
  __syncthreads();
#pragma unroll 1
  for (int ti = 0; ti < 2; ++ti) {
    int tt = wv * 2 + ti;
    int tok = tt * 16 + (lane & 15);
    s16x8 bfr[4];
#pragma unroll
    for (int kk = 0; kk < 4; ++kk)
      bfr[kk] = *(const s16x8*)(smem + BUF0 + tok * 256 +
                                swz(tok, kk * 64 + (lane >> 4) * 16));
    bool tokValid = tok < TOK;
    int tdd = tok / 36, trr = tok - tdd * 36;
    int thh = trr / 6, tww = trr - thh * 6;
    int pos = boff + tdd * 2304 + thh * 48 + tww;
#pragma unroll 1
    for (int jt = 0; jt < 8; ++jt) {
      f32x4 acc = {};
#pragma unroll
      for (int kk = 0; kk < 4; ++kk) {
        int rw = jt * 16 + (lane & 15);
        s16x8 af = *(const s16x8*)(smem + WOFF + rw * 256 +
                                   swz(rw, kk * 64 + (lane >> 4) * 16));
        acc = __builtin_amdgcn_mfma_f32_16x16x32_bf16(af, bfr[kk], acc, 0, 0, 0);
      }
      f32x4 pbv = *(const f32x4*)(pb + jt * 16 + (lane >> 4) * 4);
      if (tokValid) {
#pragma unroll
        for (int r = 0; r < 4; ++r) {
          int j = jt * 16 + (lane >> 4) * 4 + r;
          out[j * SP + pos] = acc[r] + pbv[r];
        }
      }
    }
  }
}

extern "C" void kernel_launch(void* const* d_in, const int* in_sizes, int n_in,
                              void* d_out, int out_size, void* d_ws, size_t ws_size,
                              hipStream_t stream) {
  const float* qm  = (const float*)d_in[0];
  const float* km  = (const float*)d_in[1];
  const float* vm  = (const float*)d_in[2];
  const float* gq  = (const float*)d_in[3];
  const float* bq  = (const float*)d_in[4];
  const float* gkv = (const float*)d_in[5];
  const float* bkv = (const float*)d_in[6];
  const float* pw  = (const float*)d_in[7];
  const float* pb  = (const float*)d_in[8];
  if (ws_size >= WSNEED) {
    u16* qn  = (u16*)d_ws;                       // Q, then O in-place
    u16* kn  = (u16*)((char*)d_ws + TENB);
    u16* vn  = (u16*)((char*)d_ws + 2 * TENB);
    u16* wbf = (u16*)((char*)d_ws + 3 * TENB);
    hipLaunchKernelGGL(lnpre_kernel, dim3(2305), dim3(256), 0, stream,
                       qm, km, vm, gq, bq, gkv, bkv, pw, qn, kn, vn, wbf);
    hipLaunchKernelGGL(attnh_kernel, dim3(1024), dim3(448), 0, stream,
                       qn, kn, vn);
    hipLaunchKernelGGL(proj_kernel, dim3(2304), dim3(256), 0, stream,
                       qn, wbf, pb, (float*)d_out);
  } else {
    hipLaunchKernelGGL(ca3d_kernel, dim3(512), dim3(T1), LDS_OLD, stream,
                       qm, km, vm, gq, bq, gkv, bkv, pw, pb, (float*)d_out);
  }
}